// Round 2
// baseline (920.931 us; speedup 1.0000x reference)
//
#include <hip/hip_runtime.h>
#include <hip/hip_bf16.h>

#define H 96
#define DIN 256

// ---------- CSR build ----------
__global__ void k_hist(const int* __restrict__ ei, int E, int N, int* __restrict__ deg) {
    int e = blockIdx.x * blockDim.x + threadIdx.x;
    int Et = E + N;
    if (e >= Et) return;
    int dst = (e < E) ? ei[E + e] : (e - E);
    atomicAdd(&deg[dst], 1);
}

__global__ void k_scan(const int* __restrict__ deg, int* __restrict__ rs, int* __restrict__ cur, int n) {
    __shared__ int buf[1024];
    __shared__ int carry_s;
    int t = threadIdx.x;
    if (t == 0) carry_s = 0;
    __syncthreads();
    for (int base = 0; base < n; base += 1024) {
        int i = base + t;
        int v = (i < n) ? deg[i] : 0;
        buf[t] = v;
        __syncthreads();
        for (int off = 1; off < 1024; off <<= 1) {
            int tmp = (t >= off) ? buf[t - off] : 0;
            __syncthreads();
            buf[t] += tmp;
            __syncthreads();
        }
        int excl = carry_s + buf[t] - v;
        if (i < n) { rs[i] = excl; cur[i] = excl; }
        __syncthreads();
        if (t == 0) carry_s += buf[1023];
        __syncthreads();
    }
    if (t == 0) rs[n] = carry_s;
}

__global__ void k_scatter(const int* __restrict__ ei, int E, int N,
                          int* __restrict__ cur, int* __restrict__ csr_src, int* __restrict__ csr_dst) {
    int e = blockIdx.x * blockDim.x + threadIdx.x;
    int Et = E + N;
    if (e >= Et) return;
    int src, dst;
    if (e < E) { src = ei[e]; dst = ei[E + e]; }
    else       { src = e - E; dst = e - E; }
    int pos = atomicAdd(&cur[dst], 1);
    csr_src[pos] = src;
    csr_dst[pos] = dst;
}

// ---------- xt = x @ W_in^T + b_in  (K=256) ----------
__global__ __launch_bounds__(256) void k_gemm_in(const float* __restrict__ x, const float* __restrict__ W,
                                                 const float* __restrict__ b, float* __restrict__ xt, int N) {
    __shared__ float xs[16][65];
    __shared__ float Ws[96][65];
    int t = threadIdx.x;
    int r = t & 15, ci = t >> 4;   // ci in [0,16): cols ci*6 .. ci*6+5
    int row0 = blockIdx.x * 16;
    float acc[6] = {0, 0, 0, 0, 0, 0};
    for (int k0 = 0; k0 < DIN; k0 += 64) {
        for (int idx = t; idx < 16 * 64; idx += 256) {
            int rr = idx >> 6, kk = idx & 63;
            int gr = row0 + rr;
            xs[rr][kk] = (gr < N) ? x[gr * DIN + k0 + kk] : 0.f;
        }
        for (int idx = t; idx < 96 * 64; idx += 256) {
            int cc = idx >> 6, kk = idx & 63;
            Ws[cc][kk] = W[cc * DIN + k0 + kk];
        }
        __syncthreads();
        for (int k = 0; k < 64; k++) {
            float xv = xs[r][k];
#pragma unroll
            for (int j = 0; j < 6; j++) acc[j] += xv * Ws[ci * 6 + j][k];
        }
        __syncthreads();
    }
    int gr = row0 + r;
    if (gr < N) {
#pragma unroll
        for (int j = 0; j < 6; j++) { int c = ci * 6 + j; xt[gr * H + c] = acc[j] + b[c]; }
    }
}

// ---------- h_N = h + tanh(h@Wb1^T + A@Wb2^T + bb1 + bb2)  (K=96) ----------
__global__ __launch_bounds__(256) void k_gemm_gate(const float* __restrict__ h, const float* __restrict__ A,
                                                   const float* __restrict__ W1, const float* __restrict__ W2,
                                                   const float* __restrict__ b1, const float* __restrict__ b2,
                                                   float* __restrict__ out, int N) {
    __shared__ float hs[16][33], as_[16][33];
    __shared__ float W1s[96][33], W2s[96][33];
    int t = threadIdx.x;
    int r = t & 15, ci = t >> 4;
    int row0 = blockIdx.x * 16;
    float acc[6] = {0, 0, 0, 0, 0, 0};
    for (int k0 = 0; k0 < H; k0 += 32) {
        for (int idx = t; idx < 16 * 32; idx += 256) {
            int rr = idx >> 5, kk = idx & 31;
            int gr = row0 + rr;
            hs[rr][kk]  = (gr < N) ? h[gr * H + k0 + kk] : 0.f;
            as_[rr][kk] = (gr < N) ? A[gr * H + k0 + kk] : 0.f;
        }
        for (int idx = t; idx < 96 * 32; idx += 256) {
            int cc = idx >> 5, kk = idx & 31;
            W1s[cc][kk] = W1[cc * H + k0 + kk];
            W2s[cc][kk] = W2[cc * H + k0 + kk];
        }
        __syncthreads();
        for (int k = 0; k < 32; k++) {
            float hv = hs[r][k], av = as_[r][k];
#pragma unroll
            for (int j = 0; j < 6; j++) { int c = ci * 6 + j; acc[j] += hv * W1s[c][k] + av * W2s[c][k]; }
        }
        __syncthreads();
    }
    int gr = row0 + r;
    if (gr < N) {
#pragma unroll
        for (int j = 0; j < 6; j++) {
            int c = ci * 6 + j;
            float bg = tanhf(acc[j] + b1[c] + b2[c]);
            out[gr * H + c] = h[gr * H + c] + bg;
        }
    }
}

// ---------- per-node inverse L2 norm ----------
__global__ __launch_bounds__(256) void k_invnorm(const float* __restrict__ in, float* __restrict__ inv, int N) {
    int wid = (blockIdx.x * blockDim.x + threadIdx.x) >> 6;
    int lane = threadIdx.x & 63;
    if (wid >= N) return;
    const float* row = in + wid * H;
    float v0 = row[lane];
    float v1 = (lane < 32) ? row[64 + lane] : 0.f;
    float ss = v0 * v0 + v1 * v1;
#pragma unroll
    for (int off = 32; off; off >>= 1) ss += __shfl_xor(ss, off, 64);
    if (lane == 0) inv[wid] = 1.f / fmaxf(sqrtf(ss), 1e-12f);
}

// ---------- per-edge cosine (one matrix, raw feat + inv norms) ----------
__global__ void k_cos1(const float* __restrict__ feat, const float* __restrict__ inv,
                       const int* __restrict__ csr_src, const int* __restrict__ csr_dst,
                       float* __restrict__ cosv, int Et) {
    int s = blockIdx.x * blockDim.x + threadIdx.x;
    if (s >= Et) return;
    int sn = csr_src[s], dn = csr_dst[s];
    const float4* a = (const float4*)(feat + sn * H);
    const float4* b = (const float4*)(feat + dn * H);
    float acc = 0.f;
#pragma unroll
    for (int i = 0; i < 24; i++) {
        float4 u = a[i], v = b[i];
        acc += u.x * v.x + u.y * v.y + u.z * v.z + u.w * v.w;
    }
    cosv[s] = acc * inv[sn] * inv[dn];
}

// ---------- per-edge cosine (two matrices) ----------
__global__ void k_cos2(const float* __restrict__ fa, const float* __restrict__ ia,
                       const float* __restrict__ fb, const float* __restrict__ ib,
                       const int* __restrict__ csr_src, const int* __restrict__ csr_dst,
                       float* __restrict__ ca, float* __restrict__ cb, int Et) {
    int s = blockIdx.x * blockDim.x + threadIdx.x;
    if (s >= Et) return;
    int sn = csr_src[s], dn = csr_dst[s];
    int sp = sn * H, dp = dn * H;
    const float4* a1 = (const float4*)(fa + sp);
    const float4* a2 = (const float4*)(fa + dp);
    const float4* b1 = (const float4*)(fb + sp);
    const float4* b2 = (const float4*)(fb + dp);
    float accA = 0.f, accB = 0.f;
#pragma unroll
    for (int i = 0; i < 24; i++) {
        float4 u = a1[i], v = a2[i];
        accA += u.x * v.x + u.y * v.y + u.z * v.z + u.w * v.w;
        float4 p = b1[i], q = b2[i];
        accB += p.x * q.x + p.y * q.y + p.z * q.z + p.w * q.w;
    }
    ca[s] = accA * ia[sn] * ia[dn];
    cb[s] = accB * ib[sn] * ib[dn];
}

// ---------- AGNN on h (beta1): wave per node ----------
__global__ __launch_bounds__(256) void k_agnn_h(const float* __restrict__ hfeat, const float* __restrict__ cosv,
                                                const int* __restrict__ rs, const int* __restrict__ csr_src,
                                                const float* __restrict__ betas, float* __restrict__ out, int N) {
    int wid = (blockIdx.x * blockDim.x + threadIdx.x) >> 6;
    int lane = threadIdx.x & 63;
    if (wid >= N) return;
    float beta = betas[1];
    int s0 = rs[wid], s1 = rs[wid + 1];
    float m = -1e30f;
    for (int s = s0 + lane; s < s1; s += 64) m = fmaxf(m, beta * cosv[s]);
#pragma unroll
    for (int off = 32; off; off >>= 1) m = fmaxf(m, __shfl_xor(m, off, 64));
    float den = 0.f;
    for (int s = s0 + lane; s < s1; s += 64) den += __expf(beta * cosv[s] - m);
#pragma unroll
    for (int off = 32; off; off >>= 1) den += __shfl_xor(den, off, 64);
    float inv = 1.f / den;
    float a0 = 0.f, a1 = 0.f;
    for (int s = s0; s < s1; ++s) {
        float w = __expf(beta * cosv[s] - m) * inv;
        const float* row = hfeat + csr_src[s] * H;
        a0 += w * row[lane];
        if (lane < 32) a1 += w * row[64 + lane];
    }
    out[wid * H + lane] = a0;
    if (lane < 32) out[wid * H + 64 + lane] = a1;
}

// ---------- fused 8-softmax gate kernel + LSTM epilogue: wave per node ----------
__global__ __launch_bounds__(256) void k_gates(const float* __restrict__ xt, const float* __restrict__ hN,
                                               const float* __restrict__ cx, const float* __restrict__ ch,
                                               const int* __restrict__ rs, const int* __restrict__ csr_src,
                                               const float* __restrict__ betas, const float* __restrict__ cold,
                                               float* __restrict__ hout, float* __restrict__ cout_, int N) {
    int wid = (blockIdx.x * blockDim.x + threadIdx.x) >> 6;
    int lane = threadIdx.x & 63;
    if (wid >= N) return;
    float bx[4], bh[4];
#pragma unroll
    for (int g = 0; g < 4; g++) { bx[g] = betas[2 + 2 * g]; bh[g] = betas[3 + 2 * g]; }
    int s0 = rs[wid], s1 = rs[wid + 1];

    float mx[4], mh[4];
#pragma unroll
    for (int g = 0; g < 4; g++) { mx[g] = -1e30f; mh[g] = -1e30f; }
    for (int s = s0 + lane; s < s1; s += 64) {
        float c1 = cx[s], c2 = ch[s];
#pragma unroll
        for (int g = 0; g < 4; g++) {
            mx[g] = fmaxf(mx[g], bx[g] * c1);
            mh[g] = fmaxf(mh[g], bh[g] * c2);
        }
    }
#pragma unroll
    for (int g = 0; g < 4; g++) {
#pragma unroll
        for (int off = 32; off; off >>= 1) {
            mx[g] = fmaxf(mx[g], __shfl_xor(mx[g], off, 64));
            mh[g] = fmaxf(mh[g], __shfl_xor(mh[g], off, 64));
        }
    }
    float dx[4], dh[4];
#pragma unroll
    for (int g = 0; g < 4; g++) { dx[g] = 0.f; dh[g] = 0.f; }
    for (int s = s0 + lane; s < s1; s += 64) {
        float c1 = cx[s], c2 = ch[s];
#pragma unroll
        for (int g = 0; g < 4; g++) {
            dx[g] += __expf(bx[g] * c1 - mx[g]);
            dh[g] += __expf(bh[g] * c2 - mh[g]);
        }
    }
#pragma unroll
    for (int g = 0; g < 4; g++) {
#pragma unroll
        for (int off = 32; off; off >>= 1) {
            dx[g] += __shfl_xor(dx[g], off, 64);
            dh[g] += __shfl_xor(dh[g], off, 64);
        }
        dx[g] = 1.f / dx[g];
        dh[g] = 1.f / dh[g];
    }

    float a0[4], a1[4];
#pragma unroll
    for (int g = 0; g < 4; g++) { a0[g] = 0.f; a1[g] = 0.f; }
    for (int s = s0; s < s1; ++s) {
        float c1 = cx[s], c2 = ch[s];
        float wx[4], wh[4];
#pragma unroll
        for (int g = 0; g < 4; g++) {
            wx[g] = __expf(bx[g] * c1 - mx[g]) * dx[g];
            wh[g] = __expf(bh[g] * c2 - mh[g]) * dh[g];
        }
        const float* rx = xt + csr_src[s] * H;
        const float* rh = hN + csr_src[s] * H;
        float xv = rx[lane], hv = rh[lane];
#pragma unroll
        for (int g = 0; g < 4; g++) a0[g] += wx[g] * xv + wh[g] * hv;
        if (lane < 32) {
            float xv1 = rx[64 + lane], hv1 = rh[64 + lane];
#pragma unroll
            for (int g = 0; g < 4; g++) a1[g] += wx[g] * xv1 + wh[g] * hv1;
        }
    }
    // epilogue d = lane
    {
        float f  = 1.f / (1.f + __expf(-a0[0]));
        float i_ = 1.f / (1.f + __expf(-a0[1]));
        float ct = tanhf(a0[2]);
        float o  = 1.f / (1.f + __expf(-a0[3]));
        float cv = cold[wid * H + lane];
        float cn = f * cv + i_ * ct;
        hout[wid * H + lane] = o * tanhf(cn);
        cout_[wid * H + lane] = cn;
    }
    if (lane < 32) {
        float f  = 1.f / (1.f + __expf(-a1[0]));
        float i_ = 1.f / (1.f + __expf(-a1[1]));
        float ct = tanhf(a1[2]);
        float o  = 1.f / (1.f + __expf(-a1[3]));
        float cv = cold[wid * H + 64 + lane];
        float cn = f * cv + i_ * ct;
        hout[wid * H + 64 + lane] = o * tanhf(cn);
        cout_[wid * H + 64 + lane] = cn;
    }
}

extern "C" void kernel_launch(void* const* d_in, const int* in_sizes, int n_in,
                              void* d_out, int out_size, void* d_ws, size_t ws_size,
                              hipStream_t stream) {
    const float* x        = (const float*)d_in[0];
    const int*   ei       = (const int*)d_in[1];    // harness delivers integers as int32
    const float* h        = (const float*)d_in[2];
    const float* c        = (const float*)d_in[3];
    const float* W_in     = (const float*)d_in[4];
    const float* b_in     = (const float*)d_in[5];
    // d_in[6..9] = Wg1,bg1,Wg2,bg2 — unused in the reference
    const float* Wb1      = (const float*)d_in[10];
    const float* bb1      = (const float*)d_in[11];
    const float* Wb2      = (const float*)d_in[12];
    const float* bb2      = (const float*)d_in[13];
    const float* betas    = (const float*)d_in[14];

    int N  = in_sizes[0] / DIN;
    int E  = in_sizes[1] / 2;
    int Et = E + N;
    int NH = N * H;

    char* ws = (char*)d_ws;
    size_t off = 0;
    auto alloc = [&](size_t bytes) -> void* {
        void* p = ws + off;
        off = (off + bytes + 255) & ~(size_t)255;
        return p;
    };
    // Phase-overlapped layout (~66 MB peak):
    float* xt    = (float*)alloc((size_t)NH * 4);            // xt, lives whole run
    float* big1  = (float*)alloc((size_t)NH * 4);            // h_N0; later cosX+cosN
    float* big2  = (float*)alloc((size_t)NH * 4);            // cosH (first Et floats); later h_N
    int* csr_src = (int*)alloc((size_t)Et * 4);
    int* csr_dst = (int*)alloc((size_t)Et * 4);
    int* deg     = (int*)alloc((size_t)N * 4);
    int* rs      = (int*)alloc((size_t)(N + 1) * 4);
    int* cur     = (int*)alloc((size_t)N * 4);
    float* inv_h  = (float*)alloc((size_t)N * 4);
    float* inv_xt = (float*)alloc((size_t)N * 4);
    float* inv_hN = (float*)alloc((size_t)N * 4);

    float* hN0  = big1;           // phase C/D
    float* cosX = big1;           // phase E/F (after hN0 dead)
    float* cosN = big1 + Et;
    float* cosH = big2;           // phase C (before h_N written)
    float* hN   = big2;           // phase D onward

    hipMemsetAsync(deg, 0, (size_t)N * 4, stream);
    k_hist<<<(Et + 255) / 256, 256, 0, stream>>>(ei, E, N, deg);
    k_scan<<<1, 1024, 0, stream>>>(deg, rs, cur, N);
    k_scatter<<<(Et + 255) / 256, 256, 0, stream>>>(ei, E, N, cur, csr_src, csr_dst);

    k_gemm_in<<<(N + 15) / 16, 256, 0, stream>>>(x, W_in, b_in, xt, N);

    k_invnorm<<<(N + 3) / 4, 256, 0, stream>>>(h, inv_h, N);
    k_cos1<<<(Et + 255) / 256, 256, 0, stream>>>(h, inv_h, csr_src, csr_dst, cosH, Et);
    k_agnn_h<<<(N + 3) / 4, 256, 0, stream>>>(h, cosH, rs, csr_src, betas, hN0, N);

    k_gemm_gate<<<(N + 15) / 16, 256, 0, stream>>>(h, hN0, Wb1, Wb2, bb1, bb2, hN, N);

    k_invnorm<<<(N + 3) / 4, 256, 0, stream>>>(xt, inv_xt, N);
    k_invnorm<<<(N + 3) / 4, 256, 0, stream>>>(hN, inv_hN, N);
    k_cos2<<<(Et + 255) / 256, 256, 0, stream>>>(xt, inv_xt, hN, inv_hN, csr_src, csr_dst, cosX, cosN, Et);

    float* hout = (float*)d_out;
    float* cout_ = (float*)d_out + NH;
    k_gates<<<(N + 3) / 4, 256, 0, stream>>>(xt, hN, cosX, cosN, rs, csr_src, betas, c, hout, cout_, N);
}

// Round 5
// 596.790 us; speedup vs baseline: 1.5431x; 1.5431x over previous
//
#include <hip/hip_runtime.h>
#include <hip/hip_bf16.h>

#define H 96
#define DIN 256

// ---------- CSR build ----------
__global__ void k_hist(const int* __restrict__ ei, int E, int N, int* __restrict__ deg) {
    int e = blockIdx.x * blockDim.x + threadIdx.x;
    int Et = E + N;
    if (e >= Et) return;
    int dst = (e < E) ? ei[E + e] : (e - E);
    atomicAdd(&deg[dst], 1);
}

// 3-kernel parallel exclusive scan of deg[0..n) -> rs
__global__ __launch_bounds__(256) void k_scanA(const int* __restrict__ deg, int* __restrict__ rs,
                                               int* __restrict__ bsum, int n) {
    __shared__ int sh[256];
    int t = threadIdx.x;
    int base = blockIdx.x * 1024 + t * 4;
    int v[4];
    int s = 0;
#pragma unroll
    for (int j = 0; j < 4; j++) { v[j] = (base + j < n) ? deg[base + j] : 0; s += v[j]; }
    sh[t] = s;
    __syncthreads();
    for (int off = 1; off < 256; off <<= 1) {
        int tmp = (t >= off) ? sh[t - off] : 0;
        __syncthreads();
        sh[t] += tmp;
        __syncthreads();
    }
    int excl = sh[t] - s;
#pragma unroll
    for (int j = 0; j < 4; j++) {
        if (base + j < n) rs[base + j] = excl;
        excl += v[j];
    }
    if (t == 255) bsum[blockIdx.x] = sh[255];
}

__global__ void k_scanB(int* __restrict__ bsum, int nb) {
    int l = threadIdx.x;  // single block of 64
    int orig = (l < nb) ? bsum[l] : 0;
    int v = orig;
#pragma unroll
    for (int off = 1; off < 64; off <<= 1) {
        int u = __shfl_up(v, off, 64);
        if (l >= off) v += u;
    }
    if (l < nb) bsum[l] = v - orig;  // exclusive
}

__global__ void k_scanC(int* __restrict__ rs, int* __restrict__ cur, const int* __restrict__ bsum,
                        int n, int total) {
    int i = blockIdx.x * blockDim.x + threadIdx.x;
    if (i < n) {
        int r = rs[i] + bsum[i >> 10];
        rs[i] = r;
        cur[i] = r;
    }
    if (i == 0) rs[n] = total;
}

__global__ void k_scatter(const int* __restrict__ ei, int E, int N,
                          int* __restrict__ cur, int* __restrict__ csr_src) {
    int e = blockIdx.x * blockDim.x + threadIdx.x;
    int Et = E + N;
    if (e >= Et) return;
    int src, dst;
    if (e < E) { src = ei[e]; dst = ei[E + e]; }
    else       { src = e - E; dst = e - E; }
    int pos = atomicAdd(&cur[dst], 1);
    csr_src[pos] = src;
}

// ---------- xt = x @ W_in^T + b_in  (K=256) ----------
__global__ __launch_bounds__(256) void k_gemm_in(const float* __restrict__ x, const float* __restrict__ W,
                                                 const float* __restrict__ b, float* __restrict__ xt, int N) {
    __shared__ float xs[16][65];
    __shared__ float Ws[96][65];
    int t = threadIdx.x;
    int r = t & 15, ci = t >> 4;
    int row0 = blockIdx.x * 16;
    float acc[6] = {0, 0, 0, 0, 0, 0};
    for (int k0 = 0; k0 < DIN; k0 += 64) {
        for (int idx = t; idx < 16 * 64; idx += 256) {
            int rr = idx >> 6, kk = idx & 63;
            int gr = row0 + rr;
            xs[rr][kk] = (gr < N) ? x[gr * DIN + k0 + kk] : 0.f;
        }
        for (int idx = t; idx < 96 * 64; idx += 256) {
            int cc = idx >> 6, kk = idx & 63;
            Ws[cc][kk] = W[cc * DIN + k0 + kk];
        }
        __syncthreads();
        for (int k = 0; k < 64; k++) {
            float xv = xs[r][k];
#pragma unroll
            for (int j = 0; j < 6; j++) acc[j] += xv * Ws[ci * 6 + j][k];
        }
        __syncthreads();
    }
    int gr = row0 + r;
    if (gr < N) {
#pragma unroll
        for (int j = 0; j < 6; j++) { int c = ci * 6 + j; xt[gr * H + c] = acc[j] + b[c]; }
    }
}

// ---------- h_N = h + tanh(h@Wb1^T + A@Wb2^T + bb1 + bb2)  (K=96) ----------
__global__ __launch_bounds__(256) void k_gemm_gate(const float* __restrict__ h, const float* __restrict__ A,
                                                   const float* __restrict__ W1, const float* __restrict__ W2,
                                                   const float* __restrict__ b1, const float* __restrict__ b2,
                                                   float* __restrict__ out, int N) {
    __shared__ float hs[16][33], as_[16][33];
    __shared__ float W1s[96][33], W2s[96][33];
    int t = threadIdx.x;
    int r = t & 15, ci = t >> 4;
    int row0 = blockIdx.x * 16;
    float acc[6] = {0, 0, 0, 0, 0, 0};
    for (int k0 = 0; k0 < H; k0 += 32) {
        for (int idx = t; idx < 16 * 32; idx += 256) {
            int rr = idx >> 5, kk = idx & 31;
            int gr = row0 + rr;
            hs[rr][kk]  = (gr < N) ? h[gr * H + k0 + kk] : 0.f;
            as_[rr][kk] = (gr < N) ? A[gr * H + k0 + kk] : 0.f;
        }
        for (int idx = t; idx < 96 * 32; idx += 256) {
            int cc = idx >> 5, kk = idx & 31;
            W1s[cc][kk] = W1[cc * H + k0 + kk];
            W2s[cc][kk] = W2[cc * H + k0 + kk];
        }
        __syncthreads();
        for (int k = 0; k < 32; k++) {
            float hv = hs[r][k], av = as_[r][k];
#pragma unroll
            for (int j = 0; j < 6; j++) { int c = ci * 6 + j; acc[j] += hv * W1s[c][k] + av * W2s[c][k]; }
        }
        __syncthreads();
    }
    int gr = row0 + r;
    if (gr < N) {
#pragma unroll
        for (int j = 0; j < 6; j++) {
            int c = ci * 6 + j;
            float bg = tanhf(acc[j] + b1[c] + b2[c]);
            out[gr * H + c] = h[gr * H + c] + bg;
        }
    }
}

// ---------- per-node inverse L2 norm ----------
__global__ __launch_bounds__(256) void k_invnorm(const float* __restrict__ in, float* __restrict__ inv, int N) {
    int wid = (blockIdx.x * blockDim.x + threadIdx.x) >> 6;
    int lane = threadIdx.x & 63;
    if (wid >= N) return;
    const float* row = in + (size_t)wid * H;
    float v0 = row[lane];
    float v1 = (lane < 32) ? row[64 + lane] : 0.f;
    float ss = v0 * v0 + v1 * v1;
#pragma unroll
    for (int off = 32; off; off >>= 1) ss += __shfl_xor(ss, off, 64);
    if (lane == 0) inv[wid] = 1.f / fmaxf(sqrtf(ss), 1e-12f);
}

// ---------- fused AGNN on h: cos + static-shift softmax + accumulate, wave/node ----------
// softmax shift-invariance: alpha = beta*cos in [-|beta|,|beta|]; use shift=|beta| (>= true max).
__global__ __launch_bounds__(256) void k_fused_h(const float* __restrict__ hfeat, const float* __restrict__ invn,
                                                 const int* __restrict__ rs, const int* __restrict__ csr_src,
                                                 const float* __restrict__ betas, float* __restrict__ out, int N) {
    int wid = (blockIdx.x * blockDim.x + threadIdx.x) >> 6;
    int lane = threadIdx.x & 63;
    if (wid >= N) return;
    float beta = betas[1];
    float shift = fabsf(beta);
    const float* drow = hfeat + (size_t)wid * H;
    float invd = invn[wid];
    float dn0 = drow[lane] * invd;
    float dn1 = (lane < 32) ? drow[64 + lane] * invd : 0.f;
    int s0 = rs[wid], s1 = rs[wid + 1];
    float den = 0.f, acc0 = 0.f, acc1 = 0.f;
    for (int s = s0; s < s1; ++s) {
        int sn = csr_src[s];
        const float* srow = hfeat + (size_t)sn * H;
        float v0 = srow[lane];
        float v1 = (lane < 32) ? srow[64 + lane] : 0.f;
        float invs = invn[sn];
        float d = v0 * dn0 + v1 * dn1;
#pragma unroll
        for (int off = 32; off; off >>= 1) d += __shfl_xor(d, off, 64);
        float w = __expf(beta * (d * invs) - shift);
        den += w;
        acc0 += w * v0;
        acc1 += w * v1;
    }
    float r = 1.f / den;
    out[(size_t)wid * H + lane] = acc0 * r;
    if (lane < 32) out[(size_t)wid * H + 64 + lane] = acc1 * r;
}

// ---------- fused gate kernel: 2 cosines, 8 static-shift softmaxes, 4 gates + LSTM ----------
__global__ __launch_bounds__(256) void k_fused_gates(const float* __restrict__ xt, const float* __restrict__ hN,
                                                     const float* __restrict__ invx, const float* __restrict__ invh,
                                                     const int* __restrict__ rs, const int* __restrict__ csr_src,
                                                     const float* __restrict__ betas, const float* __restrict__ cold,
                                                     float* __restrict__ hout, float* __restrict__ cout_, int N) {
    int wid = (blockIdx.x * blockDim.x + threadIdx.x) >> 6;
    int lane = threadIdx.x & 63;
    if (wid >= N) return;
    float bx[4], bh[4], sx[4], sh_[4];
#pragma unroll
    for (int g = 0; g < 4; g++) {
        bx[g] = betas[2 + 2 * g]; bh[g] = betas[3 + 2 * g];
        sx[g] = fabsf(bx[g]);     sh_[g] = fabsf(bh[g]);
    }
    const float* xd = xt + (size_t)wid * H;
    const float* hd = hN + (size_t)wid * H;
    float ix = invx[wid], ih = invh[wid];
    float xnd0 = xd[lane] * ix;
    float xnd1 = (lane < 32) ? xd[64 + lane] * ix : 0.f;
    float hnd0 = hd[lane] * ih;
    float hnd1 = (lane < 32) ? hd[64 + lane] * ih : 0.f;

    int s0 = rs[wid], s1 = rs[wid + 1];
    float denX[4] = {0, 0, 0, 0}, denH[4] = {0, 0, 0, 0};
    float aX0[4] = {0, 0, 0, 0}, aX1[4] = {0, 0, 0, 0};
    float aH0[4] = {0, 0, 0, 0}, aH1[4] = {0, 0, 0, 0};
    for (int s = s0; s < s1; ++s) {
        int sn = csr_src[s];
        const float* xs_ = xt + (size_t)sn * H;
        const float* hs_ = hN + (size_t)sn * H;
        float xv0 = xs_[lane];
        float xv1 = (lane < 32) ? xs_[64 + lane] : 0.f;
        float hv0 = hs_[lane];
        float hv1 = (lane < 32) ? hs_[64 + lane] : 0.f;
        float isx = invx[sn], ish = invh[sn];
        float dx = xv0 * xnd0 + xv1 * xnd1;
        float dh = hv0 * hnd0 + hv1 * hnd1;
#pragma unroll
        for (int off = 32; off; off >>= 1) {
            dx += __shfl_xor(dx, off, 64);
            dh += __shfl_xor(dh, off, 64);
        }
        float cx = dx * isx;
        float ch = dh * ish;
#pragma unroll
        for (int g = 0; g < 4; g++) {
            float wx = __expf(bx[g] * cx - sx[g]);
            float wh = __expf(bh[g] * ch - sh_[g]);
            denX[g] += wx; denH[g] += wh;
            aX0[g] += wx * xv0; aX1[g] += wx * xv1;
            aH0[g] += wh * hv0; aH1[g] += wh * hv1;
        }
    }
    // epilogue
    {
        float a0 = aX0[0] / denX[0] + aH0[0] / denH[0];
        float a1 = aX0[1] / denX[1] + aH0[1] / denH[1];
        float a2 = aX0[2] / denX[2] + aH0[2] / denH[2];
        float a3 = aX0[3] / denX[3] + aH0[3] / denH[3];
        float f  = 1.f / (1.f + __expf(-a0));
        float i_ = 1.f / (1.f + __expf(-a1));
        float ct = tanhf(a2);
        float o  = 1.f / (1.f + __expf(-a3));
        float cv = cold[(size_t)wid * H + lane];
        float cn = f * cv + i_ * ct;
        hout[(size_t)wid * H + lane] = o * tanhf(cn);
        cout_[(size_t)wid * H + lane] = cn;
    }
    if (lane < 32) {
        float a0 = aX1[0] / denX[0] + aH1[0] / denH[0];
        float a1 = aX1[1] / denX[1] + aH1[1] / denH[1];
        float a2 = aX1[2] / denX[2] + aH1[2] / denH[2];
        float a3 = aX1[3] / denX[3] + aH1[3] / denH[3];
        float f  = 1.f / (1.f + __expf(-a0));
        float i_ = 1.f / (1.f + __expf(-a1));
        float ct = tanhf(a2);
        float o  = 1.f / (1.f + __expf(-a3));
        float cv = cold[(size_t)wid * H + 64 + lane];
        float cn = f * cv + i_ * ct;
        hout[(size_t)wid * H + 64 + lane] = o * tanhf(cn);
        cout_[(size_t)wid * H + 64 + lane] = cn;
    }
}

extern "C" void kernel_launch(void* const* d_in, const int* in_sizes, int n_in,
                              void* d_out, int out_size, void* d_ws, size_t ws_size,
                              hipStream_t stream) {
    const float* x        = (const float*)d_in[0];
    const int*   ei       = (const int*)d_in[1];
    const float* h        = (const float*)d_in[2];
    const float* c        = (const float*)d_in[3];
    const float* W_in     = (const float*)d_in[4];
    const float* b_in     = (const float*)d_in[5];
    const float* Wb1      = (const float*)d_in[10];
    const float* bb1      = (const float*)d_in[11];
    const float* Wb2      = (const float*)d_in[12];
    const float* bb2      = (const float*)d_in[13];
    const float* betas    = (const float*)d_in[14];

    int N  = in_sizes[0] / DIN;
    int E  = in_sizes[1] / 2;
    int Et = E + N;
    int NH = N * H;

    char* ws = (char*)d_ws;
    size_t off = 0;
    auto alloc = [&](size_t bytes) -> void* {
        void* p = ws + off;
        off = (off + bytes + 255) & ~(size_t)255;
        return p;
    };
    float* xt    = (float*)alloc((size_t)NH * 4);
    float* hN0   = (float*)alloc((size_t)NH * 4);
    float* hN    = (float*)alloc((size_t)NH * 4);
    int* csr_src = (int*)alloc((size_t)Et * 4);
    int* deg     = (int*)alloc((size_t)N * 4);
    int* rs      = (int*)alloc((size_t)(N + 1) * 4);
    int* cur     = (int*)alloc((size_t)N * 4);
    int* bsum    = (int*)alloc(64 * 4);
    float* inv_h  = (float*)alloc((size_t)N * 4);
    float* inv_xt = (float*)alloc((size_t)N * 4);
    float* inv_hN = (float*)alloc((size_t)N * 4);

    int nb = (N + 1023) / 1024;  // scan blocks (<= 64)

    hipMemsetAsync(deg, 0, (size_t)N * 4, stream);
    k_hist<<<(Et + 255) / 256, 256, 0, stream>>>(ei, E, N, deg);
    k_scanA<<<nb, 256, 0, stream>>>(deg, rs, bsum, N);
    k_scanB<<<1, 64, 0, stream>>>(bsum, nb);
    k_scanC<<<(N + 255) / 256, 256, 0, stream>>>(rs, cur, bsum, N, Et);
    k_scatter<<<(Et + 255) / 256, 256, 0, stream>>>(ei, E, N, cur, csr_src);

    k_gemm_in<<<(N + 15) / 16, 256, 0, stream>>>(x, W_in, b_in, xt, N);

    k_invnorm<<<(N + 3) / 4, 256, 0, stream>>>(h, inv_h, N);
    k_fused_h<<<(N + 3) / 4, 256, 0, stream>>>(h, inv_h, rs, csr_src, betas, hN0, N);

    k_gemm_gate<<<(N + 15) / 16, 256, 0, stream>>>(h, hN0, Wb1, Wb2, bb1, bb2, hN, N);

    k_invnorm<<<(N + 3) / 4, 256, 0, stream>>>(xt, inv_xt, N);
    k_invnorm<<<(N + 3) / 4, 256, 0, stream>>>(hN, inv_hN, N);

    float* hout = (float*)d_out;
    float* cout_ = (float*)d_out + NH;
    k_fused_gates<<<(N + 3) / 4, 256, 0, stream>>>(xt, hN, inv_xt, inv_hN, rs, csr_src, betas, c, hout, cout_, N);
}

// Round 7
// 522.079 us; speedup vs baseline: 1.7640x; 1.1431x over previous
//
#include <hip/hip_runtime.h>
#include <hip/hip_bf16.h>

#define H 96
#define DIN 256

// ---------- CSR build ----------
__global__ void k_hist(const int* __restrict__ ei, int E, int N, int* __restrict__ deg) {
    int e = blockIdx.x * blockDim.x + threadIdx.x;
    int Et = E + N;
    if (e >= Et) return;
    int dst = (e < E) ? ei[E + e] : (e - E);
    atomicAdd(&deg[dst], 1);
}

// 3-kernel parallel exclusive scan of deg[0..n) -> rs
__global__ __launch_bounds__(256) void k_scanA(const int* __restrict__ deg, int* __restrict__ rs,
                                               int* __restrict__ bsum, int n) {
    __shared__ int sh[256];
    int t = threadIdx.x;
    int base = blockIdx.x * 1024 + t * 4;
    int v[4];
    int s = 0;
#pragma unroll
    for (int j = 0; j < 4; j++) { v[j] = (base + j < n) ? deg[base + j] : 0; s += v[j]; }
    sh[t] = s;
    __syncthreads();
    for (int off = 1; off < 256; off <<= 1) {
        int tmp = (t >= off) ? sh[t - off] : 0;
        __syncthreads();
        sh[t] += tmp;
        __syncthreads();
    }
    int excl = sh[t] - s;
#pragma unroll
    for (int j = 0; j < 4; j++) {
        if (base + j < n) rs[base + j] = excl;
        excl += v[j];
    }
    if (t == 255) bsum[blockIdx.x] = sh[255];
}

__global__ void k_scanB(int* __restrict__ bsum, int nb) {
    int l = threadIdx.x;  // single block of 64
    int orig = (l < nb) ? bsum[l] : 0;
    int v = orig;
#pragma unroll
    for (int off = 1; off < 64; off <<= 1) {
        int u = __shfl_up(v, off, 64);
        if (l >= off) v += u;
    }
    if (l < nb) bsum[l] = v - orig;  // exclusive
}

__global__ void k_scanC(int* __restrict__ rs, int* __restrict__ cur, const int* __restrict__ bsum,
                        int n, int total) {
    int i = blockIdx.x * blockDim.x + threadIdx.x;
    if (i < n) {
        int r = rs[i] + bsum[i >> 10];
        rs[i] = r;
        cur[i] = r;
    }
    if (i == 0) rs[n] = total;
}

__global__ void k_scatter(const int* __restrict__ ei, int E, int N,
                          int* __restrict__ cur, int* __restrict__ csr_src) {
    int e = blockIdx.x * blockDim.x + threadIdx.x;
    int Et = E + N;
    if (e >= Et) return;
    int src, dst;
    if (e < E) { src = ei[e]; dst = ei[E + e]; }
    else       { src = e - E; dst = e - E; }
    int pos = atomicAdd(&cur[dst], 1);
    csr_src[pos] = src;
}

// ---------- xt = x @ W_in^T + b_in  (K=256) ----------
__global__ __launch_bounds__(256) void k_gemm_in(const float* __restrict__ x, const float* __restrict__ W,
                                                 const float* __restrict__ b, float* __restrict__ xt, int N) {
    __shared__ float xs[16][65];
    __shared__ float Ws[96][65];
    int t = threadIdx.x;
    int r = t & 15, ci = t >> 4;
    int row0 = blockIdx.x * 16;
    float acc[6] = {0, 0, 0, 0, 0, 0};
    for (int k0 = 0; k0 < DIN; k0 += 64) {
        for (int idx = t; idx < 16 * 64; idx += 256) {
            int rr = idx >> 6, kk = idx & 63;
            int gr = row0 + rr;
            xs[rr][kk] = (gr < N) ? x[gr * DIN + k0 + kk] : 0.f;
        }
        for (int idx = t; idx < 96 * 64; idx += 256) {
            int cc = idx >> 6, kk = idx & 63;
            Ws[cc][kk] = W[cc * DIN + k0 + kk];
        }
        __syncthreads();
        for (int k = 0; k < 64; k++) {
            float xv = xs[r][k];
#pragma unroll
            for (int j = 0; j < 6; j++) acc[j] += xv * Ws[ci * 6 + j][k];
        }
        __syncthreads();
    }
    int gr = row0 + r;
    if (gr < N) {
#pragma unroll
        for (int j = 0; j < 6; j++) { int c = ci * 6 + j; xt[gr * H + c] = acc[j] + b[c]; }
    }
}

// ---------- h_N = h + tanh(h@Wb1^T + A@Wb2^T + bb1 + bb2)  (K=96) ----------
__global__ __launch_bounds__(256) void k_gemm_gate(const float* __restrict__ h, const float* __restrict__ A,
                                                   const float* __restrict__ W1, const float* __restrict__ W2,
                                                   const float* __restrict__ b1, const float* __restrict__ b2,
                                                   float* __restrict__ out, int N) {
    __shared__ float hs[16][33], as_[16][33];
    __shared__ float W1s[96][33], W2s[96][33];
    int t = threadIdx.x;
    int r = t & 15, ci = t >> 4;
    int row0 = blockIdx.x * 16;
    float acc[6] = {0, 0, 0, 0, 0, 0};
    for (int k0 = 0; k0 < H; k0 += 32) {
        for (int idx = t; idx < 16 * 32; idx += 256) {
            int rr = idx >> 5, kk = idx & 31;
            int gr = row0 + rr;
            hs[rr][kk]  = (gr < N) ? h[gr * H + k0 + kk] : 0.f;
            as_[rr][kk] = (gr < N) ? A[gr * H + k0 + kk] : 0.f;
        }
        for (int idx = t; idx < 96 * 32; idx += 256) {
            int cc = idx >> 5, kk = idx & 31;
            W1s[cc][kk] = W1[cc * H + k0 + kk];
            W2s[cc][kk] = W2[cc * H + k0 + kk];
        }
        __syncthreads();
        for (int k = 0; k < 32; k++) {
            float hv = hs[r][k], av = as_[r][k];
#pragma unroll
            for (int j = 0; j < 6; j++) { int c = ci * 6 + j; acc[j] += hv * W1s[c][k] + av * W2s[c][k]; }
        }
        __syncthreads();
    }
    int gr = row0 + r;
    if (gr < N) {
#pragma unroll
        for (int j = 0; j < 6; j++) {
            int c = ci * 6 + j;
            float bg = tanhf(acc[j] + b1[c] + b2[c]);
            out[gr * H + c] = h[gr * H + c] + bg;
        }
    }
}

// ---------- per-node inverse L2 norm ----------
__global__ __launch_bounds__(256) void k_invnorm(const float* __restrict__ in, float* __restrict__ inv, int N) {
    int wid = (blockIdx.x * blockDim.x + threadIdx.x) >> 6;
    int lane = threadIdx.x & 63;
    if (wid >= N) return;
    const float* row = in + (size_t)wid * H;
    float v0 = row[lane];
    float v1 = (lane < 32) ? row[64 + lane] : 0.f;
    float ss = v0 * v0 + v1 * v1;
#pragma unroll
    for (int off = 32; off; off >>= 1) ss += __shfl_xor(ss, off, 64);
    if (lane == 0) inv[wid] = 1.f / fmaxf(sqrtf(ss), 1e-12f);
}

// ---------- fused AGNN on h: quarter-wave (16 lanes/edge, 4 edges/iter) ----------
// softmax shift-invariance: alpha = beta*cos in [-|beta|,|beta|]; shift=|beta| >= true max.
__global__ __launch_bounds__(256) void k_fused_h(const float* __restrict__ hfeat, const float* __restrict__ invn,
                                                 const int* __restrict__ rs, const int* __restrict__ csr_src,
                                                 const float* __restrict__ betas, float* __restrict__ out, int N) {
    int wid = (blockIdx.x * blockDim.x + threadIdx.x) >> 6;
    int lane = threadIdx.x & 63;
    if (wid >= N) return;
    int fi = lane & 15;
    int q  = lane >> 4;
    float beta = betas[1];
    float shift = fabsf(beta);
    const float* drow = hfeat + (size_t)wid * H;
    float invd = invn[wid];
    float dn[6];
#pragma unroll
    for (int j = 0; j < 6; j++) dn[j] = drow[16 * j + fi] * invd;
    int s0 = rs[wid], s1 = rs[wid + 1];
    float den = 0.f;
    float acc[6] = {0, 0, 0, 0, 0, 0};
    for (int s = s0; s < s1; s += 4) {
        int idx = s + q;
        bool valid = idx < s1;
        int sidx = valid ? idx : s;
        int sn = csr_src[sidx];
        float invs = invn[sn];
        const float* srow = hfeat + (size_t)sn * H;
        float v[6];
#pragma unroll
        for (int j = 0; j < 6; j++) v[j] = srow[16 * j + fi];
        float d = 0.f;
#pragma unroll
        for (int j = 0; j < 6; j++) d += v[j] * dn[j];
#pragma unroll
        for (int off = 8; off; off >>= 1) d += __shfl_xor(d, off, 64);
        float w = __expf(beta * (d * invs) - shift);
        if (!valid) w = 0.f;
        den += w;
#pragma unroll
        for (int j = 0; j < 6; j++) acc[j] += w * v[j];
    }
    den += __shfl_xor(den, 16, 64);
    den += __shfl_xor(den, 32, 64);
#pragma unroll
    for (int j = 0; j < 6; j++) {
        acc[j] += __shfl_xor(acc[j], 16, 64);
        acc[j] += __shfl_xor(acc[j], 32, 64);
    }
    if (q == 0) {
        float r = 1.f / den;
#pragma unroll
        for (int j = 0; j < 6; j++) out[(size_t)wid * H + 16 * j + fi] = acc[j] * r;
    }
}

// ---------- fused gate kernel: quarter-wave, uniform-beta fast path ----------
__global__ __launch_bounds__(256) void k_fused_gates(const float* __restrict__ xt, const float* __restrict__ hN,
                                                     const float* __restrict__ invx, const float* __restrict__ invh,
                                                     const int* __restrict__ rs, const int* __restrict__ csr_src,
                                                     const float* __restrict__ betas, const float* __restrict__ cold,
                                                     float* __restrict__ hout, float* __restrict__ cout_, int N) {
    int wid = (blockIdx.x * blockDim.x + threadIdx.x) >> 6;
    int lane = threadIdx.x & 63;
    if (wid >= N) return;
    int fi = lane & 15;
    int q  = lane >> 4;
    float bx0 = betas[2], bh0 = betas[3];
    float bx1 = betas[4], bh1 = betas[5];
    float bx2 = betas[6], bh2 = betas[7];
    float bx3 = betas[8], bh3 = betas[9];
    bool uni = (bx0 == bx1) && (bx0 == bx2) && (bx0 == bx3) &&
               (bh0 == bh1) && (bh0 == bh2) && (bh0 == bh3);

    const float* xd = xt + (size_t)wid * H;
    const float* hd = hN + (size_t)wid * H;
    float ixd = invx[wid], ihd = invh[wid];
    float xn[6], hn[6];
#pragma unroll
    for (int j = 0; j < 6; j++) {
        xn[j] = xd[16 * j + fi] * ixd;
        hn[j] = hd[16 * j + fi] * ihd;
    }
    int s0 = rs[wid], s1 = rs[wid + 1];
    size_t rowbase = (size_t)wid * H;

    if (uni) {
        // all 4 gates share identical softmax weights
        float sxs = fabsf(bx0), shs = fabsf(bh0);
        float denX = 0.f, denH = 0.f;
        float aX[6] = {0, 0, 0, 0, 0, 0}, aH[6] = {0, 0, 0, 0, 0, 0};
        for (int s = s0; s < s1; s += 4) {
            int idx = s + q;
            bool valid = idx < s1;
            int sidx = valid ? idx : s;
            int sn = csr_src[sidx];
            float isx = invx[sn], ish = invh[sn];
            const float* xs_ = xt + (size_t)sn * H;
            const float* hs_ = hN + (size_t)sn * H;
            float xv[6], hv[6];
#pragma unroll
            for (int j = 0; j < 6; j++) { xv[j] = xs_[16 * j + fi]; hv[j] = hs_[16 * j + fi]; }
            float dx = 0.f, dh = 0.f;
#pragma unroll
            for (int j = 0; j < 6; j++) { dx += xv[j] * xn[j]; dh += hv[j] * hn[j]; }
#pragma unroll
            for (int off = 8; off; off >>= 1) {
                dx += __shfl_xor(dx, off, 64);
                dh += __shfl_xor(dh, off, 64);
            }
            float wx = __expf(bx0 * (dx * isx) - sxs);
            float wh = __expf(bh0 * (dh * ish) - shs);
            if (!valid) { wx = 0.f; wh = 0.f; }
            denX += wx; denH += wh;
#pragma unroll
            for (int j = 0; j < 6; j++) { aX[j] += wx * xv[j]; aH[j] += wh * hv[j]; }
        }
        denX += __shfl_xor(denX, 16, 64); denX += __shfl_xor(denX, 32, 64);
        denH += __shfl_xor(denH, 16, 64); denH += __shfl_xor(denH, 32, 64);
#pragma unroll
        for (int j = 0; j < 6; j++) {
            aX[j] += __shfl_xor(aX[j], 16, 64); aX[j] += __shfl_xor(aX[j], 32, 64);
            aH[j] += __shfl_xor(aH[j], 16, 64); aH[j] += __shfl_xor(aH[j], 32, 64);
        }
        if (q == 0) {
            float rX = 1.f / denX, rH = 1.f / denH;
#pragma unroll
            for (int j = 0; j < 6; j++) {
                int d = 16 * j + fi;
                float a   = aX[j] * rX + aH[j] * rH;
                float sig = 1.f / (1.f + __expf(-a));   // f = i = o
                float ct  = tanhf(a);                   // c_tilde
                float cv  = cold[rowbase + d];
                float cn  = sig * cv + sig * ct;
                hout[rowbase + d]  = sig * tanhf(cn);
                cout_[rowbase + d] = cn;
            }
        }
    } else {
        // general 4-gate path
        float sx[4] = {fabsf(bx0), fabsf(bx1), fabsf(bx2), fabsf(bx3)};
        float sh_[4] = {fabsf(bh0), fabsf(bh1), fabsf(bh2), fabsf(bh3)};
        float bxv[4] = {bx0, bx1, bx2, bx3};
        float bhv[4] = {bh0, bh1, bh2, bh3};
        float denX[4] = {0, 0, 0, 0}, denH[4] = {0, 0, 0, 0};
        float aX[4][6], aH[4][6];
#pragma unroll
        for (int g = 0; g < 4; g++)
#pragma unroll
            for (int j = 0; j < 6; j++) { aX[g][j] = 0.f; aH[g][j] = 0.f; }
        for (int s = s0; s < s1; s += 4) {
            int idx = s + q;
            bool valid = idx < s1;
            int sidx = valid ? idx : s;
            int sn = csr_src[sidx];
            float isx = invx[sn], ish = invh[sn];
            const float* xs_ = xt + (size_t)sn * H;
            const float* hs_ = hN + (size_t)sn * H;
            float xv[6], hv[6];
#pragma unroll
            for (int j = 0; j < 6; j++) { xv[j] = xs_[16 * j + fi]; hv[j] = hs_[16 * j + fi]; }
            float dx = 0.f, dh = 0.f;
#pragma unroll
            for (int j = 0; j < 6; j++) { dx += xv[j] * xn[j]; dh += hv[j] * hn[j]; }
#pragma unroll
            for (int off = 8; off; off >>= 1) {
                dx += __shfl_xor(dx, off, 64);
                dh += __shfl_xor(dh, off, 64);
            }
            float cx = dx * isx, ch = dh * ish;
#pragma unroll
            for (int g = 0; g < 4; g++) {
                float wx = __expf(bxv[g] * cx - sx[g]);
                float wh = __expf(bhv[g] * ch - sh_[g]);
                if (!valid) { wx = 0.f; wh = 0.f; }
                denX[g] += wx; denH[g] += wh;
#pragma unroll
                for (int j = 0; j < 6; j++) { aX[g][j] += wx * xv[j]; aH[g][j] += wh * hv[j]; }
            }
        }
#pragma unroll
        for (int g = 0; g < 4; g++) {
            denX[g] += __shfl_xor(denX[g], 16, 64); denX[g] += __shfl_xor(denX[g], 32, 64);
            denH[g] += __shfl_xor(denH[g], 16, 64); denH[g] += __shfl_xor(denH[g], 32, 64);
#pragma unroll
            for (int j = 0; j < 6; j++) {
                aX[g][j] += __shfl_xor(aX[g][j], 16, 64); aX[g][j] += __shfl_xor(aX[g][j], 32, 64);
                aH[g][j] += __shfl_xor(aH[g][j], 16, 64); aH[g][j] += __shfl_xor(aH[g][j], 32, 64);
            }
        }
        if (q == 0) {
#pragma unroll
            for (int j = 0; j < 6; j++) {
                int d = 16 * j + fi;
                float a0 = aX[0][j] / denX[0] + aH[0][j] / denH[0];
                float a1 = aX[1][j] / denX[1] + aH[1][j] / denH[1];
                float a2 = aX[2][j] / denX[2] + aH[2][j] / denH[2];
                float a3 = aX[3][j] / denX[3] + aH[3][j] / denH[3];
                float f  = 1.f / (1.f + __expf(-a0));
                float i_ = 1.f / (1.f + __expf(-a1));
                float ct = tanhf(a2);
                float o  = 1.f / (1.f + __expf(-a3));
                float cv = cold[rowbase + d];
                float cn = f * cv + i_ * ct;
                hout[rowbase + d]  = o * tanhf(cn);
                cout_[rowbase + d] = cn;
            }
        }
    }
}

extern "C" void kernel_launch(void* const* d_in, const int* in_sizes, int n_in,
                              void* d_out, int out_size, void* d_ws, size_t ws_size,
                              hipStream_t stream) {
    const float* x        = (const float*)d_in[0];
    const int*   ei       = (const int*)d_in[1];
    const float* h        = (const float*)d_in[2];
    const float* c        = (const float*)d_in[3];
    const float* W_in     = (const float*)d_in[4];
    const float* b_in     = (const float*)d_in[5];
    const float* Wb1      = (const float*)d_in[10];
    const float* bb1      = (const float*)d_in[11];
    const float* Wb2      = (const float*)d_in[12];
    const float* bb2      = (const float*)d_in[13];
    const float* betas    = (const float*)d_in[14];

    int N  = in_sizes[0] / DIN;
    int E  = in_sizes[1] / 2;
    int Et = E + N;
    int NH = N * H;

    char* ws = (char*)d_ws;
    size_t off = 0;
    auto alloc = [&](size_t bytes) -> void* {
        void* p = ws + off;
        off = (off + bytes + 255) & ~(size_t)255;
        return p;
    };
    float* xt    = (float*)alloc((size_t)NH * 4);
    float* hN0   = (float*)alloc((size_t)NH * 4);
    float* hN    = (float*)alloc((size_t)NH * 4);
    int* csr_src = (int*)alloc((size_t)Et * 4);
    int* deg     = (int*)alloc((size_t)N * 4);
    int* rs      = (int*)alloc((size_t)(N + 1) * 4);
    int* cur     = (int*)alloc((size_t)N * 4);
    int* bsum    = (int*)alloc(64 * 4);
    float* inv_h  = (float*)alloc((size_t)N * 4);
    float* inv_xt = (float*)alloc((size_t)N * 4);
    float* inv_hN = (float*)alloc((size_t)N * 4);

    int nb = (N + 1023) / 1024;  // scan blocks (<= 64)

    hipMemsetAsync(deg, 0, (size_t)N * 4, stream);
    k_hist<<<(Et + 255) / 256, 256, 0, stream>>>(ei, E, N, deg);
    k_scanA<<<nb, 256, 0, stream>>>(deg, rs, bsum, N);
    k_scanB<<<1, 64, 0, stream>>>(bsum, nb);
    k_scanC<<<(N + 255) / 256, 256, 0, stream>>>(rs, cur, bsum, N, Et);
    k_scatter<<<(Et + 255) / 256, 256, 0, stream>>>(ei, E, N, cur, csr_src);

    k_gemm_in<<<(N + 15) / 16, 256, 0, stream>>>(x, W_in, b_in, xt, N);

    k_invnorm<<<(N + 3) / 4, 256, 0, stream>>>(h, inv_h, N);
    k_fused_h<<<(N + 3) / 4, 256, 0, stream>>>(h, inv_h, rs, csr_src, betas, hN0, N);

    k_gemm_gate<<<(N + 15) / 16, 256, 0, stream>>>(h, hN0, Wb1, Wb2, bb1, bb2, hN, N);

    k_invnorm<<<(N + 3) / 4, 256, 0, stream>>>(xt, inv_xt, N);
    k_invnorm<<<(N + 3) / 4, 256, 0, stream>>>(hN, inv_hN, N);

    float* hout = (float*)d_out;
    float* cout_ = (float*)d_out + NH;
    k_fused_gates<<<(N + 3) / 4, 256, 0, stream>>>(xt, hN, inv_xt, inv_hN, rs, csr_src, betas, c, hout, cout_, N);
}

// Round 8
// 455.364 us; speedup vs baseline: 2.0224x; 1.1465x over previous
//
#include <hip/hip_runtime.h>
#include <hip/hip_bf16.h>

#define H 96
#define DIN 256

typedef unsigned int uint32;

__device__ __forceinline__ float bflo(uint32 u) { return __uint_as_float(u << 16); }
__device__ __forceinline__ float bfhi(uint32 u) { return __uint_as_float(u & 0xffff0000u); }
__device__ __forceinline__ uint32 packbf(float a, float b) {
    __hip_bfloat16 x = __float2bfloat16(a), y = __float2bfloat16(b);
    unsigned short lo = *reinterpret_cast<unsigned short*>(&x);
    unsigned short hi = *reinterpret_cast<unsigned short*>(&y);
    return (uint32)lo | ((uint32)hi << 16);
}

// ---------- CSR build ----------
__global__ void k_hist(const int* __restrict__ ei, int E, int N, int* __restrict__ deg) {
    int e = blockIdx.x * blockDim.x + threadIdx.x;
    int Et = E + N;
    if (e >= Et) return;
    int dst = (e < E) ? ei[E + e] : (e - E);
    atomicAdd(&deg[dst], 1);
}

__global__ __launch_bounds__(256) void k_scanA(const int* __restrict__ deg, int* __restrict__ rs,
                                               int* __restrict__ bsum, int n) {
    __shared__ int sh[256];
    int t = threadIdx.x;
    int base = blockIdx.x * 1024 + t * 4;
    int v[4];
    int s = 0;
#pragma unroll
    for (int j = 0; j < 4; j++) { v[j] = (base + j < n) ? deg[base + j] : 0; s += v[j]; }
    sh[t] = s;
    __syncthreads();
    for (int off = 1; off < 256; off <<= 1) {
        int tmp = (t >= off) ? sh[t - off] : 0;
        __syncthreads();
        sh[t] += tmp;
        __syncthreads();
    }
    int excl = sh[t] - s;
#pragma unroll
    for (int j = 0; j < 4; j++) {
        if (base + j < n) rs[base + j] = excl;
        excl += v[j];
    }
    if (t == 255) bsum[blockIdx.x] = sh[255];
}

__global__ void k_scanB(int* __restrict__ bsum, int nb) {
    int l = threadIdx.x;
    int orig = (l < nb) ? bsum[l] : 0;
    int v = orig;
#pragma unroll
    for (int off = 1; off < 64; off <<= 1) {
        int u = __shfl_up(v, off, 64);
        if (l >= off) v += u;
    }
    if (l < nb) bsum[l] = v - orig;
}

__global__ void k_scanC(int* __restrict__ rs, int* __restrict__ cur, const int* __restrict__ bsum,
                        int n, int total) {
    int i = blockIdx.x * blockDim.x + threadIdx.x;
    if (i < n) {
        int r = rs[i] + bsum[i >> 10];
        rs[i] = r;
        cur[i] = r;
    }
    if (i == 0) rs[n] = total;
}

__global__ void k_scatter(const int* __restrict__ ei, int E, int N,
                          int* __restrict__ cur, int* __restrict__ csr_src) {
    int e = blockIdx.x * blockDim.x + threadIdx.x;
    int Et = E + N;
    if (e >= Et) return;
    int src, dst;
    if (e < E) { src = ei[e]; dst = ei[E + e]; }
    else       { src = e - E; dst = e - E; }
    int pos = atomicAdd(&cur[dst], 1);
    csr_src[pos] = src;
}

// ---------- xt = x @ W_in^T + b_in  (K=256), output bf16 rows ----------
__global__ __launch_bounds__(256) void k_gemm_in(const float* __restrict__ x, const float* __restrict__ W,
                                                 const float* __restrict__ b, uint32* __restrict__ xtb, int N) {
    __shared__ float xs[16][65];
    __shared__ float Ws[96][65];
    int t = threadIdx.x;
    int r = t & 15, ci = t >> 4;
    int row0 = blockIdx.x * 16;
    float acc[6] = {0, 0, 0, 0, 0, 0};
    for (int k0 = 0; k0 < DIN; k0 += 64) {
        for (int idx = t; idx < 16 * 64; idx += 256) {
            int rr = idx >> 6, kk = idx & 63;
            int gr = row0 + rr;
            xs[rr][kk] = (gr < N) ? x[gr * DIN + k0 + kk] : 0.f;
        }
        for (int idx = t; idx < 96 * 64; idx += 256) {
            int cc = idx >> 6, kk = idx & 63;
            Ws[cc][kk] = W[cc * DIN + k0 + kk];
        }
        __syncthreads();
        for (int k = 0; k < 64; k++) {
            float xv = xs[r][k];
#pragma unroll
            for (int j = 0; j < 6; j++) acc[j] += xv * Ws[ci * 6 + j][k];
        }
        __syncthreads();
    }
    int gr = row0 + r;
    if (gr < N) {
        int c = ci * 6;
        uint32* orow = xtb + (size_t)gr * 48 + ci * 3;
        orow[0] = packbf(acc[0] + b[c + 0], acc[1] + b[c + 1]);
        orow[1] = packbf(acc[2] + b[c + 2], acc[3] + b[c + 3]);
        orow[2] = packbf(acc[4] + b[c + 4], acc[5] + b[c + 5]);
    }
}

// ---------- h_N = h + tanh(h@Wb1^T + A@Wb2^T + bb1 + bb2), output bf16 rows ----------
__global__ __launch_bounds__(256) void k_gemm_gate(const float* __restrict__ h, const float* __restrict__ A,
                                                   const float* __restrict__ W1, const float* __restrict__ W2,
                                                   const float* __restrict__ b1, const float* __restrict__ b2,
                                                   uint32* __restrict__ hNb, int N) {
    __shared__ float hs[16][33], as_[16][33];
    __shared__ float W1s[96][33], W2s[96][33];
    int t = threadIdx.x;
    int r = t & 15, ci = t >> 4;
    int row0 = blockIdx.x * 16;
    float acc[6] = {0, 0, 0, 0, 0, 0};
    for (int k0 = 0; k0 < H; k0 += 32) {
        for (int idx = t; idx < 16 * 32; idx += 256) {
            int rr = idx >> 5, kk = idx & 31;
            int gr = row0 + rr;
            hs[rr][kk]  = (gr < N) ? h[gr * H + k0 + kk] : 0.f;
            as_[rr][kk] = (gr < N) ? A[gr * H + k0 + kk] : 0.f;
        }
        for (int idx = t; idx < 96 * 32; idx += 256) {
            int cc = idx >> 5, kk = idx & 31;
            W1s[cc][kk] = W1[cc * H + k0 + kk];
            W2s[cc][kk] = W2[cc * H + k0 + kk];
        }
        __syncthreads();
        for (int k = 0; k < 32; k++) {
            float hv = hs[r][k], av = as_[r][k];
#pragma unroll
            for (int j = 0; j < 6; j++) { int c = ci * 6 + j; acc[j] += hv * W1s[c][k] + av * W2s[c][k]; }
        }
        __syncthreads();
    }
    int gr = row0 + r;
    if (gr < N) {
        float v[6];
#pragma unroll
        for (int j = 0; j < 6; j++) {
            int c = ci * 6 + j;
            v[j] = h[gr * H + c] + tanhf(acc[j] + b1[c] + b2[c]);
        }
        uint32* orow = hNb + (size_t)gr * 48 + ci * 3;
        orow[0] = packbf(v[0], v[1]);
        orow[1] = packbf(v[2], v[3]);
        orow[2] = packbf(v[4], v[5]);
    }
}

// ---------- h (f32) -> bf16 table + inverse norm (norm from rounded values) ----------
__global__ __launch_bounds__(256) void k_cvt_h(const float* __restrict__ h, uint32* __restrict__ hb,
                                               float* __restrict__ inv, int N) {
    int wid = (blockIdx.x * blockDim.x + threadIdx.x) >> 6;
    int lane = threadIdx.x & 63;
    if (wid >= N) return;
    const float2* row = (const float2*)(h + (size_t)wid * H);
    float ss = 0.f;
    if (lane < 48) {
        float2 v = row[lane];
        uint32 p = packbf(v.x, v.y);
        hb[(size_t)wid * 48 + lane] = p;
        float a = bflo(p), b = bfhi(p);
        ss = a * a + b * b;
    }
#pragma unroll
    for (int off = 32; off; off >>= 1) ss += __shfl_xor(ss, off, 64);
    if (lane == 0) inv[wid] = 1.f / fmaxf(sqrtf(ss), 1e-12f);
}

// ---------- inverse norm of a bf16 table ----------
__global__ __launch_bounds__(256) void k_invnorm_b(const uint32* __restrict__ tb, float* __restrict__ inv, int N) {
    int wid = (blockIdx.x * blockDim.x + threadIdx.x) >> 6;
    int lane = threadIdx.x & 63;
    if (wid >= N) return;
    float ss = 0.f;
    if (lane < 48) {
        uint32 u = tb[(size_t)wid * 48 + lane];
        float a = bflo(u), b = bfhi(u);
        ss = a * a + b * b;
    }
#pragma unroll
    for (int off = 32; off; off >>= 1) ss += __shfl_xor(ss, off, 64);
    if (lane == 0) inv[wid] = 1.f / fmaxf(sqrtf(ss), 1e-12f);
}

// ---------- fused AGNN on h: quarter-wave, bf16 rows, 2-deep pipeline ----------
__global__ __launch_bounds__(256) void k_fused_h(const uint32* __restrict__ hb, const float* __restrict__ invn,
                                                 const int* __restrict__ rs, const int* __restrict__ csr_src,
                                                 const float* __restrict__ betas, float* __restrict__ out, int N) {
    int wid = (blockIdx.x * blockDim.x + threadIdx.x) >> 6;
    int lane = threadIdx.x & 63;
    if (wid >= N) return;
    int fi = lane & 15;
    int q  = lane >> 4;
    float beta = betas[1];
    float shift = fabsf(beta);
    const uint32* drp = hb + (size_t)wid * 48 + 3 * fi;
    float invd = invn[wid];
    uint32 du0 = drp[0], du1 = drp[1], du2 = drp[2];
    float dn[6] = {bflo(du0) * invd, bfhi(du0) * invd, bflo(du1) * invd,
                   bfhi(du1) * invd, bflo(du2) * invd, bfhi(du2) * invd};
    int s0 = rs[wid], s1 = rs[wid + 1];
    int nIter = (s1 - s0 + 3) >> 2;
    int idx0 = s0 + q;
    bool vC = idx0 < s1;
    int snC = csr_src[vC ? idx0 : s0];
    const uint32* rp = hb + (size_t)snC * 48 + 3 * fi;
    uint32 c0 = rp[0], c1 = rp[1], c2 = rp[2];
    float invC = invn[snC];

    float den = 0.f;
    float acc[6] = {0, 0, 0, 0, 0, 0};
    for (int it = 0; it < nIter; ++it) {
        // prefetch next quad
        int idxN = idx0 + 4 * (it + 1);
        bool vN = idxN < s1;
        int snN = csr_src[vN ? idxN : s0];
        const uint32* rpn = hb + (size_t)snN * 48 + 3 * fi;
        uint32 n0 = rpn[0], n1 = rpn[1], n2 = rpn[2];
        float invN = invn[snN];
        // compute current
        float v[6] = {bflo(c0), bfhi(c0), bflo(c1), bfhi(c1), bflo(c2), bfhi(c2)};
        float d = 0.f;
#pragma unroll
        for (int j = 0; j < 6; j++) d += v[j] * dn[j];
#pragma unroll
        for (int off = 8; off; off >>= 1) d += __shfl_xor(d, off, 64);
        float w = __expf(beta * (d * invC) - shift);
        if (!vC) w = 0.f;
        den += w;
#pragma unroll
        for (int j = 0; j < 6; j++) acc[j] += w * v[j];
        c0 = n0; c1 = n1; c2 = n2; invC = invN; vC = vN;
    }
    den += __shfl_xor(den, 16, 64);
    den += __shfl_xor(den, 32, 64);
#pragma unroll
    for (int j = 0; j < 6; j++) {
        acc[j] += __shfl_xor(acc[j], 16, 64);
        acc[j] += __shfl_xor(acc[j], 32, 64);
    }
    if (q == 0) {
        float r = 1.f / den;
        float2* op = (float2*)(out + (size_t)wid * H + 6 * fi);
        op[0] = make_float2(acc[0] * r, acc[1] * r);
        op[1] = make_float2(acc[2] * r, acc[3] * r);
        op[2] = make_float2(acc[4] * r, acc[5] * r);
    }
}

// ---------- fused gate kernel: quarter-wave, bf16 rows, pipeline, uniform-beta fast path ----------
__global__ __launch_bounds__(256) void k_fused_gates(const uint32* __restrict__ xtb, const uint32* __restrict__ hNb,
                                                     const float* __restrict__ invx, const float* __restrict__ invh,
                                                     const int* __restrict__ rs, const int* __restrict__ csr_src,
                                                     const float* __restrict__ betas, const float* __restrict__ cold,
                                                     float* __restrict__ hout, float* __restrict__ cout_, int N) {
    int wid = (blockIdx.x * blockDim.x + threadIdx.x) >> 6;
    int lane = threadIdx.x & 63;
    if (wid >= N) return;
    int fi = lane & 15;
    int q  = lane >> 4;
    float bx0 = betas[2], bh0 = betas[3];
    float bx1 = betas[4], bh1 = betas[5];
    float bx2 = betas[6], bh2 = betas[7];
    float bx3 = betas[8], bh3 = betas[9];
    bool uni = (bx0 == bx1) && (bx0 == bx2) && (bx0 == bx3) &&
               (bh0 == bh1) && (bh0 == bh2) && (bh0 == bh3);

    const uint32* xdp = xtb + (size_t)wid * 48 + 3 * fi;
    const uint32* hdp = hNb + (size_t)wid * 48 + 3 * fi;
    float ixd = invx[wid], ihd = invh[wid];
    uint32 xu0 = xdp[0], xu1 = xdp[1], xu2 = xdp[2];
    uint32 hu0 = hdp[0], hu1 = hdp[1], hu2 = hdp[2];
    float xn[6] = {bflo(xu0) * ixd, bfhi(xu0) * ixd, bflo(xu1) * ixd,
                   bfhi(xu1) * ixd, bflo(xu2) * ixd, bfhi(xu2) * ixd};
    float hn[6] = {bflo(hu0) * ihd, bfhi(hu0) * ihd, bflo(hu1) * ihd,
                   bfhi(hu1) * ihd, bflo(hu2) * ihd, bfhi(hu2) * ihd};
    int s0 = rs[wid], s1 = rs[wid + 1];
    size_t rowbase = (size_t)wid * H;

    if (uni) {
        float sxs = fabsf(bx0), shs = fabsf(bh0);
        int nIter = (s1 - s0 + 3) >> 2;
        int idx0 = s0 + q;
        bool vC = idx0 < s1;
        int snC = csr_src[vC ? idx0 : s0];
        const uint32* xrp = xtb + (size_t)snC * 48 + 3 * fi;
        const uint32* hrp = hNb + (size_t)snC * 48 + 3 * fi;
        uint32 xc0 = xrp[0], xc1 = xrp[1], xc2 = xrp[2];
        uint32 hc0 = hrp[0], hc1 = hrp[1], hc2 = hrp[2];
        float isxC = invx[snC], ishC = invh[snC];

        float denX = 0.f, denH = 0.f;
        float aX[6] = {0, 0, 0, 0, 0, 0}, aH[6] = {0, 0, 0, 0, 0, 0};
        for (int it = 0; it < nIter; ++it) {
            // prefetch next quad
            int idxN = idx0 + 4 * (it + 1);
            bool vN = idxN < s1;
            int snN = csr_src[vN ? idxN : s0];
            const uint32* xrn = xtb + (size_t)snN * 48 + 3 * fi;
            const uint32* hrn = hNb + (size_t)snN * 48 + 3 * fi;
            uint32 xn0 = xrn[0], xn1 = xrn[1], xn2 = xrn[2];
            uint32 hn0 = hrn[0], hn1 = hrn[1], hn2 = hrn[2];
            float isxN = invx[snN], ishN = invh[snN];
            // compute current
            float xv[6] = {bflo(xc0), bfhi(xc0), bflo(xc1), bfhi(xc1), bflo(xc2), bfhi(xc2)};
            float hv[6] = {bflo(hc0), bfhi(hc0), bflo(hc1), bfhi(hc1), bflo(hc2), bfhi(hc2)};
            float dx = 0.f, dh = 0.f;
#pragma unroll
            for (int j = 0; j < 6; j++) { dx += xv[j] * xn[j]; dh += hv[j] * hn[j]; }
#pragma unroll
            for (int off = 8; off; off >>= 1) {
                dx += __shfl_xor(dx, off, 64);
                dh += __shfl_xor(dh, off, 64);
            }
            float wx = __expf(bx0 * (dx * isxC) - sxs);
            float wh = __expf(bh0 * (dh * ishC) - shs);
            if (!vC) { wx = 0.f; wh = 0.f; }
            denX += wx; denH += wh;
#pragma unroll
            for (int j = 0; j < 6; j++) { aX[j] += wx * xv[j]; aH[j] += wh * hv[j]; }
            xc0 = xn0; xc1 = xn1; xc2 = xn2;
            hc0 = hn0; hc1 = hn1; hc2 = hn2;
            isxC = isxN; ishC = ishN; vC = vN;
        }
        denX += __shfl_xor(denX, 16, 64); denX += __shfl_xor(denX, 32, 64);
        denH += __shfl_xor(denH, 16, 64); denH += __shfl_xor(denH, 32, 64);
#pragma unroll
        for (int j = 0; j < 6; j++) {
            aX[j] += __shfl_xor(aX[j], 16, 64); aX[j] += __shfl_xor(aX[j], 32, 64);
            aH[j] += __shfl_xor(aH[j], 16, 64); aH[j] += __shfl_xor(aH[j], 32, 64);
        }
        if (q == 0) {
            float rX = 1.f / denX, rH = 1.f / denH;
            const float2* cp = (const float2*)(cold + rowbase + 6 * fi);
            float2 cv01 = cp[0], cv23 = cp[1], cv45 = cp[2];
            float cvv[6] = {cv01.x, cv01.y, cv23.x, cv23.y, cv45.x, cv45.y};
            float ho[6], co[6];
#pragma unroll
            for (int j = 0; j < 6; j++) {
                float a   = aX[j] * rX + aH[j] * rH;
                float sig = 1.f / (1.f + __expf(-a));   // f = i = o
                float ct  = tanhf(a);
                float cn  = sig * cvv[j] + sig * ct;
                ho[j] = sig * tanhf(cn);
                co[j] = cn;
            }
            float2* hp = (float2*)(hout + rowbase + 6 * fi);
            float2* cpw = (float2*)(cout_ + rowbase + 6 * fi);
            hp[0] = make_float2(ho[0], ho[1]); hp[1] = make_float2(ho[2], ho[3]); hp[2] = make_float2(ho[4], ho[5]);
            cpw[0] = make_float2(co[0], co[1]); cpw[1] = make_float2(co[2], co[3]); cpw[2] = make_float2(co[4], co[5]);
        }
    } else {
        // general 4-gate path (correctness fallback, no pipeline)
        float sx[4] = {fabsf(bx0), fabsf(bx1), fabsf(bx2), fabsf(bx3)};
        float sh_[4] = {fabsf(bh0), fabsf(bh1), fabsf(bh2), fabsf(bh3)};
        float bxv[4] = {bx0, bx1, bx2, bx3};
        float bhv[4] = {bh0, bh1, bh2, bh3};
        float denX[4] = {0, 0, 0, 0}, denH[4] = {0, 0, 0, 0};
        float aX[4][6], aH[4][6];
#pragma unroll
        for (int g = 0; g < 4; g++)
#pragma unroll
            for (int j = 0; j < 6; j++) { aX[g][j] = 0.f; aH[g][j] = 0.f; }
        for (int s = s0; s < s1; s += 4) {
            int idx = s + q;
            bool valid = idx < s1;
            int sidx = valid ? idx : s0;
            int sn = csr_src[sidx];
            float isx = invx[sn], ish = invh[sn];
            const uint32* xrp = xtb + (size_t)sn * 48 + 3 * fi;
            const uint32* hrp = hNb + (size_t)sn * 48 + 3 * fi;
            uint32 a0 = xrp[0], a1 = xrp[1], a2 = xrp[2];
            uint32 b0 = hrp[0], b1 = hrp[1], b2 = hrp[2];
            float xv[6] = {bflo(a0), bfhi(a0), bflo(a1), bfhi(a1), bflo(a2), bfhi(a2)};
            float hv[6] = {bflo(b0), bfhi(b0), bflo(b1), bfhi(b1), bflo(b2), bfhi(b2)};
            float dx = 0.f, dh = 0.f;
#pragma unroll
            for (int j = 0; j < 6; j++) { dx += xv[j] * xn[j]; dh += hv[j] * hn[j]; }
#pragma unroll
            for (int off = 8; off; off >>= 1) {
                dx += __shfl_xor(dx, off, 64);
                dh += __shfl_xor(dh, off, 64);
            }
            float cx = dx * isx, ch = dh * ish;
#pragma unroll
            for (int g = 0; g < 4; g++) {
                float wx = __expf(bxv[g] * cx - sx[g]);
                float wh = __expf(bhv[g] * ch - sh_[g]);
                if (!valid) { wx = 0.f; wh = 0.f; }
                denX[g] += wx; denH[g] += wh;
#pragma unroll
                for (int j = 0; j < 6; j++) { aX[g][j] += wx * xv[j]; aH[g][j] += wh * hv[j]; }
            }
        }
#pragma unroll
        for (int g = 0; g < 4; g++) {
            denX[g] += __shfl_xor(denX[g], 16, 64); denX[g] += __shfl_xor(denX[g], 32, 64);
            denH[g] += __shfl_xor(denH[g], 16, 64); denH[g] += __shfl_xor(denH[g], 32, 64);
#pragma unroll
            for (int j = 0; j < 6; j++) {
                aX[g][j] += __shfl_xor(aX[g][j], 16, 64); aX[g][j] += __shfl_xor(aX[g][j], 32, 64);
                aH[g][j] += __shfl_xor(aH[g][j], 16, 64); aH[g][j] += __shfl_xor(aH[g][j], 32, 64);
            }
        }
        if (q == 0) {
#pragma unroll
            for (int j = 0; j < 6; j++) {
                int d = 6 * fi + j;
                float a0 = aX[0][j] / denX[0] + aH[0][j] / denH[0];
                float a1 = aX[1][j] / denX[1] + aH[1][j] / denH[1];
                float a2 = aX[2][j] / denX[2] + aH[2][j] / denH[2];
                float a3 = aX[3][j] / denX[3] + aH[3][j] / denH[3];
                float f  = 1.f / (1.f + __expf(-a0));
                float i_ = 1.f / (1.f + __expf(-a1));
                float ct = tanhf(a2);
                float o  = 1.f / (1.f + __expf(-a3));
                float cv = cold[rowbase + d];
                float cn = f * cv + i_ * ct;
                hout[rowbase + d]  = o * tanhf(cn);
                cout_[rowbase + d] = cn;
            }
        }
    }
}

extern "C" void kernel_launch(void* const* d_in, const int* in_sizes, int n_in,
                              void* d_out, int out_size, void* d_ws, size_t ws_size,
                              hipStream_t stream) {
    const float* x        = (const float*)d_in[0];
    const int*   ei       = (const int*)d_in[1];
    const float* h        = (const float*)d_in[2];
    const float* c        = (const float*)d_in[3];
    const float* W_in     = (const float*)d_in[4];
    const float* b_in     = (const float*)d_in[5];
    const float* Wb1      = (const float*)d_in[10];
    const float* bb1      = (const float*)d_in[11];
    const float* Wb2      = (const float*)d_in[12];
    const float* bb2      = (const float*)d_in[13];
    const float* betas    = (const float*)d_in[14];

    int N  = in_sizes[0] / DIN;
    int E  = in_sizes[1] / 2;
    int Et = E + N;
    int NH = N * H;

    char* ws = (char*)d_ws;
    size_t off = 0;
    auto alloc = [&](size_t bytes) -> void* {
        void* p = ws + off;
        off = (off + bytes + 255) & ~(size_t)255;
        return p;
    };
    uint32* xtb  = (uint32*)alloc((size_t)N * 48 * 4);   // xt bf16 rows
    uint32* hNb  = (uint32*)alloc((size_t)N * 48 * 4);   // h_N bf16 rows
    uint32* hb   = (uint32*)alloc((size_t)N * 48 * 4);   // h bf16 rows
    float*  hN0  = (float*)alloc((size_t)NH * 4);        // f32 AGNN(h) output
    int* csr_src = (int*)alloc((size_t)Et * 4);
    int* deg     = (int*)alloc((size_t)N * 4);
    int* rs      = (int*)alloc((size_t)(N + 1) * 4);
    int* cur     = (int*)alloc((size_t)N * 4);
    int* bsum    = (int*)alloc(64 * 4);
    float* inv_h  = (float*)alloc((size_t)N * 4);
    float* inv_xt = (float*)alloc((size_t)N * 4);
    float* inv_hN = (float*)alloc((size_t)N * 4);

    int nb = (N + 1023) / 1024;

    hipMemsetAsync(deg, 0, (size_t)N * 4, stream);
    k_hist<<<(Et + 255) / 256, 256, 0, stream>>>(ei, E, N, deg);
    k_scanA<<<nb, 256, 0, stream>>>(deg, rs, bsum, N);
    k_scanB<<<1, 64, 0, stream>>>(bsum, nb);
    k_scanC<<<(N + 255) / 256, 256, 0, stream>>>(rs, cur, bsum, N, Et);
    k_scatter<<<(Et + 255) / 256, 256, 0, stream>>>(ei, E, N, cur, csr_src);

    k_gemm_in<<<(N + 15) / 16, 256, 0, stream>>>(x, W_in, b_in, xtb, N);
    k_cvt_h<<<(N + 3) / 4, 256, 0, stream>>>(h, hb, inv_h, N);
    k_fused_h<<<(N + 3) / 4, 256, 0, stream>>>(hb, inv_h, rs, csr_src, betas, hN0, N);

    k_gemm_gate<<<(N + 15) / 16, 256, 0, stream>>>(h, hN0, Wb1, Wb2, bb1, bb2, hNb, N);

    k_invnorm_b<<<(N + 3) / 4, 256, 0, stream>>>(xtb, inv_xt, N);
    k_invnorm_b<<<(N + 3) / 4, 256, 0, stream>>>(hNb, inv_hN, N);

    float* hout = (float*)d_out;
    float* cout_ = (float*)d_out + NH;
    k_fused_gates<<<(N + 3) / 4, 256, 0, stream>>>(xtb, hNb, inv_xt, inv_hN, rs, csr_src, betas, c, hout, cout_, N);
}

// Round 9
// 326.438 us; speedup vs baseline: 2.8211x; 1.3949x over previous
//
#include <hip/hip_runtime.h>
#include <hip/hip_bf16.h>

#define H 96
#define DIN 256

typedef unsigned int uint32;
typedef __attribute__((ext_vector_type(8))) short bf16x8;
typedef __attribute__((ext_vector_type(4))) float f32x4;

__device__ __forceinline__ float bflo(uint32 u) { return __uint_as_float(u << 16); }
__device__ __forceinline__ float bfhi(uint32 u) { return __uint_as_float(u & 0xffff0000u); }
__device__ __forceinline__ uint32 packbf(float a, float b) {
    __hip_bfloat16 x = __float2bfloat16(a), y = __float2bfloat16(b);
    unsigned short lo = *reinterpret_cast<unsigned short*>(&x);
    unsigned short hi = *reinterpret_cast<unsigned short*>(&y);
    return (uint32)lo | ((uint32)hi << 16);
}

// ---------- CSR build ----------
__global__ void k_hist(const int* __restrict__ ei, int E, int N, int* __restrict__ deg) {
    int e = blockIdx.x * blockDim.x + threadIdx.x;
    int Et = E + N;
    if (e >= Et) return;
    int dst = (e < E) ? ei[E + e] : (e - E);
    atomicAdd(&deg[dst], 1);
}

__global__ __launch_bounds__(256) void k_scanA(const int* __restrict__ deg, int* __restrict__ rs,
                                               int* __restrict__ bsum, int n) {
    __shared__ int sh[256];
    int t = threadIdx.x;
    int base = blockIdx.x * 1024 + t * 4;
    int v[4];
    int s = 0;
#pragma unroll
    for (int j = 0; j < 4; j++) { v[j] = (base + j < n) ? deg[base + j] : 0; s += v[j]; }
    sh[t] = s;
    __syncthreads();
    for (int off = 1; off < 256; off <<= 1) {
        int tmp = (t >= off) ? sh[t - off] : 0;
        __syncthreads();
        sh[t] += tmp;
        __syncthreads();
    }
    int excl = sh[t] - s;
#pragma unroll
    for (int j = 0; j < 4; j++) {
        if (base + j < n) rs[base + j] = excl;
        excl += v[j];
    }
    if (t == 255) bsum[blockIdx.x] = sh[255];
}

__global__ void k_scanB(int* __restrict__ bsum, int nb) {
    int l = threadIdx.x;
    int orig = (l < nb) ? bsum[l] : 0;
    int v = orig;
#pragma unroll
    for (int off = 1; off < 64; off <<= 1) {
        int u = __shfl_up(v, off, 64);
        if (l >= off) v += u;
    }
    if (l < nb) bsum[l] = v - orig;
}

__global__ void k_scanC(int* __restrict__ rs, int* __restrict__ cur, const int* __restrict__ bsum,
                        int n, int total) {
    int i = blockIdx.x * blockDim.x + threadIdx.x;
    if (i < n) {
        int r = rs[i] + bsum[i >> 10];
        rs[i] = r;
        cur[i] = r;
    }
    if (i == 0) rs[n] = total;
}

__global__ void k_scatter(const int* __restrict__ ei, int E, int N,
                          int* __restrict__ cur, int* __restrict__ csr_src) {
    int e = blockIdx.x * blockDim.x + threadIdx.x;
    int Et = E + N;
    if (e >= Et) return;
    int src, dst;
    if (e < E) { src = ei[e]; dst = ei[E + e]; }
    else       { src = e - E; dst = e - E; }
    int pos = atomicAdd(&cur[dst], 1);
    csr_src[pos] = src;
}

// ---------- MFMA GEMM: xt = x @ W_in^T + b_in -> bf16 table ----------
// block: 64 rows x 96 cols, 4 waves (16 rows each). K chunked by 128.
__global__ __launch_bounds__(256) void k_gemm_in_mfma(const float* __restrict__ x, const float* __restrict__ W,
                                                      const float* __restrict__ b, uint32* __restrict__ xtb, int N) {
    __shared__ uint32 As[64 * 68];  // 64 rows x 128 bf16 (+8 pad) = 68 u32/row
    __shared__ uint32 Ws[96 * 68];
    int tid = threadIdx.x;
    int lane = tid & 63;
    int w = tid >> 6;
    int row0 = blockIdx.x * 64;
    int n = lane & 15, g = lane >> 4;

    f32x4 acc[6];
#pragma unroll
    for (int t = 0; t < 6; t++) acc[t] = (f32x4){0.f, 0.f, 0.f, 0.f};

    for (int kc = 0; kc < DIN; kc += 128) {
        // stage x tile: 64 rows x 128 f32 -> bf16
        for (int i = tid; i < 64 * 32; i += 256) {
            int r = i >> 5, seg = i & 31;
            int grow = row0 + r;
            float4 v = (grow < N) ? *(const float4*)(x + (size_t)grow * DIN + kc + seg * 4)
                                  : make_float4(0.f, 0.f, 0.f, 0.f);
            As[r * 68 + seg * 2]     = packbf(v.x, v.y);
            As[r * 68 + seg * 2 + 1] = packbf(v.z, v.w);
        }
        // stage W tile: 96 rows x 128 f32 -> bf16
        for (int i = tid; i < 96 * 32; i += 256) {
            int r = i >> 5, seg = i & 31;
            float4 v = *(const float4*)(W + (size_t)r * DIN + kc + seg * 4);
            Ws[r * 68 + seg * 2]     = packbf(v.x, v.y);
            Ws[r * 68 + seg * 2 + 1] = packbf(v.z, v.w);
        }
        __syncthreads();
#pragma unroll
        for (int s = 0; s < 4; s++) {
            int kb = s * 16 + g * 4;
            bf16x8 a = *(const bf16x8*)&As[(16 * w + n) * 68 + kb];
#pragma unroll
            for (int t = 0; t < 6; t++) {
                bf16x8 bb = *(const bf16x8*)&Ws[(16 * t + n) * 68 + kb];
                acc[t] = __builtin_amdgcn_mfma_f32_16x16x32_bf16(a, bb, acc[t], 0, 0, 0);
            }
        }
        __syncthreads();
    }
    // epilogue: bias, pair-pack bf16, store
#pragma unroll
    for (int t = 0; t < 6; t++) {
        int col = 16 * t + n;
        float bv = b[col];
#pragma unroll
        for (int r = 0; r < 4; r++) {
            int grow = row0 + 16 * w + g * 4 + r;
            float v = acc[t][r] + bv;
            float p = __shfl_xor(v, 1, 64);
            if ((n & 1) == 0 && grow < N)
                xtb[(size_t)grow * 48 + 8 * t + (n >> 1)] = packbf(v, p);
        }
    }
}

// ---------- MFMA GEMM: h_N = h + tanh([h|A] @ [Wb1|Wb2]^T + bb1+bb2) -> bf16 table ----------
// K = 192 (chunked by 96). h half reuses the bf16 hb table; A half converts hN0 f32.
__global__ __launch_bounds__(256) void k_gemm_gate_mfma(const uint32* __restrict__ hb, const float* __restrict__ hN0,
                                                        const float* __restrict__ h,
                                                        const float* __restrict__ W1, const float* __restrict__ W2,
                                                        const float* __restrict__ b1, const float* __restrict__ b2,
                                                        uint32* __restrict__ hNb, int N) {
    __shared__ uint32 As[64 * 52];  // 64 rows x 96 bf16 (+8 pad) = 52 u32/row
    __shared__ uint32 Ws[96 * 52];
    int tid = threadIdx.x;
    int lane = tid & 63;
    int w = tid >> 6;
    int row0 = blockIdx.x * 64;
    int n = lane & 15, g = lane >> 4;

    f32x4 acc[6];
#pragma unroll
    for (int t = 0; t < 6; t++) acc[t] = (f32x4){0.f, 0.f, 0.f, 0.f};

    for (int chunk = 0; chunk < 2; chunk++) {
        // stage A tile
        {
            int r = tid >> 2, j = tid & 3;   // r in [0,64), j quarter
            int grow = row0 + r;
            if (chunk == 0) {
                // copy 12 u32 from hb row
                if (grow < N) {
#pragma unroll
                    for (int m = 0; m < 3; m++) {
                        uint4 u = *(const uint4*)(hb + (size_t)grow * 48 + j * 12 + m * 4);
                        *(uint4*)&As[r * 52 + j * 12 + m * 4] = u;
                    }
                } else {
#pragma unroll
                    for (int m = 0; m < 12; m++) As[r * 52 + j * 12 + m] = 0u;
                }
            } else {
                // convert 24 f32 from hN0 row
#pragma unroll
                for (int m = 0; m < 6; m++) {
                    float4 v = (grow < N) ? *(const float4*)(hN0 + (size_t)grow * H + j * 24 + m * 4)
                                          : make_float4(0.f, 0.f, 0.f, 0.f);
                    As[r * 52 + j * 12 + m * 2]     = packbf(v.x, v.y);
                    As[r * 52 + j * 12 + m * 2 + 1] = packbf(v.z, v.w);
                }
            }
        }
        // stage W tile: 96 rows x 96 f32
        {
            const float* Wsrc = chunk ? W2 : W1;
            for (int i = tid; i < 96 * 24; i += 256) {
                int r = i / 24, seg = i % 24;
                float4 v = *(const float4*)(Wsrc + (size_t)r * H + seg * 4);
                Ws[r * 52 + seg * 2]     = packbf(v.x, v.y);
                Ws[r * 52 + seg * 2 + 1] = packbf(v.z, v.w);
            }
        }
        __syncthreads();
#pragma unroll
        for (int s = 0; s < 3; s++) {
            int kb = s * 16 + g * 4;
            bf16x8 a = *(const bf16x8*)&As[(16 * w + n) * 52 + kb];
#pragma unroll
            for (int t = 0; t < 6; t++) {
                bf16x8 bb = *(const bf16x8*)&Ws[(16 * t + n) * 52 + kb];
                acc[t] = __builtin_amdgcn_mfma_f32_16x16x32_bf16(a, bb, acc[t], 0, 0, 0);
            }
        }
        __syncthreads();
    }
    // epilogue: tanh + h add + pair-pack
#pragma unroll
    for (int t = 0; t < 6; t++) {
        int col = 16 * t + n;
        float bsum = b1[col] + b2[col];
#pragma unroll
        for (int r = 0; r < 4; r++) {
            int grow = row0 + 16 * w + g * 4 + r;
            float hval = (grow < N) ? h[(size_t)grow * H + col] : 0.f;
            float v = hval + tanhf(acc[t][r] + bsum);
            float p = __shfl_xor(v, 1, 64);
            if ((n & 1) == 0 && grow < N)
                hNb[(size_t)grow * 48 + 8 * t + (n >> 1)] = packbf(v, p);
        }
    }
}

// ---------- h (f32) -> bf16 table + inverse norm (norm from rounded values) ----------
__global__ __launch_bounds__(256) void k_cvt_h(const float* __restrict__ h, uint32* __restrict__ hb,
                                               float* __restrict__ inv, int N) {
    int wid = (blockIdx.x * blockDim.x + threadIdx.x) >> 6;
    int lane = threadIdx.x & 63;
    if (wid >= N) return;
    const float2* row = (const float2*)(h + (size_t)wid * H);
    float ss = 0.f;
    if (lane < 48) {
        float2 v = row[lane];
        uint32 p = packbf(v.x, v.y);
        hb[(size_t)wid * 48 + lane] = p;
        float a = bflo(p), b = bfhi(p);
        ss = a * a + b * b;
    }
#pragma unroll
    for (int off = 32; off; off >>= 1) ss += __shfl_xor(ss, off, 64);
    if (lane == 0) inv[wid] = 1.f / fmaxf(sqrtf(ss), 1e-12f);
}

// ---------- inverse norm of a bf16 table ----------
__global__ __launch_bounds__(256) void k_invnorm_b(const uint32* __restrict__ tb, float* __restrict__ inv, int N) {
    int wid = (blockIdx.x * blockDim.x + threadIdx.x) >> 6;
    int lane = threadIdx.x & 63;
    if (wid >= N) return;
    float ss = 0.f;
    if (lane < 48) {
        uint32 u = tb[(size_t)wid * 48 + lane];
        float a = bflo(u), b = bfhi(u);
        ss = a * a + b * b;
    }
#pragma unroll
    for (int off = 32; off; off >>= 1) ss += __shfl_xor(ss, off, 64);
    if (lane == 0) inv[wid] = 1.f / fmaxf(sqrtf(ss), 1e-12f);
}

// ---------- fused AGNN on h: quarter-wave, bf16 rows, 2-deep pipeline ----------
__global__ __launch_bounds__(256) void k_fused_h(const uint32* __restrict__ hb, const float* __restrict__ invn,
                                                 const int* __restrict__ rs, const int* __restrict__ csr_src,
                                                 const float* __restrict__ betas, float* __restrict__ out, int N) {
    int wid = (blockIdx.x * blockDim.x + threadIdx.x) >> 6;
    int lane = threadIdx.x & 63;
    if (wid >= N) return;
    int fi = lane & 15;
    int q  = lane >> 4;
    float beta = betas[1];
    float shift = fabsf(beta);
    const uint32* drp = hb + (size_t)wid * 48 + 3 * fi;
    float invd = invn[wid];
    uint32 du0 = drp[0], du1 = drp[1], du2 = drp[2];
    float dn[6] = {bflo(du0) * invd, bfhi(du0) * invd, bflo(du1) * invd,
                   bfhi(du1) * invd, bflo(du2) * invd, bfhi(du2) * invd};
    int s0 = rs[wid], s1 = rs[wid + 1];
    int nIter = (s1 - s0 + 3) >> 2;
    int idx0 = s0 + q;
    bool vC = idx0 < s1;
    int snC = csr_src[vC ? idx0 : s0];
    const uint32* rp = hb + (size_t)snC * 48 + 3 * fi;
    uint32 c0 = rp[0], c1 = rp[1], c2 = rp[2];
    float invC = invn[snC];

    float den = 0.f;
    float acc[6] = {0, 0, 0, 0, 0, 0};
    for (int it = 0; it < nIter; ++it) {
        int idxN = idx0 + 4 * (it + 1);
        bool vN = idxN < s1;
        int snN = csr_src[vN ? idxN : s0];
        const uint32* rpn = hb + (size_t)snN * 48 + 3 * fi;
        uint32 n0 = rpn[0], n1 = rpn[1], n2 = rpn[2];
        float invN = invn[snN];
        float v[6] = {bflo(c0), bfhi(c0), bflo(c1), bfhi(c1), bflo(c2), bfhi(c2)};
        float d = 0.f;
#pragma unroll
        for (int j = 0; j < 6; j++) d += v[j] * dn[j];
#pragma unroll
        for (int off = 8; off; off >>= 1) d += __shfl_xor(d, off, 64);
        float w = __expf(beta * (d * invC) - shift);
        if (!vC) w = 0.f;
        den += w;
#pragma unroll
        for (int j = 0; j < 6; j++) acc[j] += w * v[j];
        c0 = n0; c1 = n1; c2 = n2; invC = invN; vC = vN;
    }
    den += __shfl_xor(den, 16, 64);
    den += __shfl_xor(den, 32, 64);
#pragma unroll
    for (int j = 0; j < 6; j++) {
        acc[j] += __shfl_xor(acc[j], 16, 64);
        acc[j] += __shfl_xor(acc[j], 32, 64);
    }
    if (q == 0) {
        float r = 1.f / den;
        float2* op = (float2*)(out + (size_t)wid * H + 6 * fi);
        op[0] = make_float2(acc[0] * r, acc[1] * r);
        op[1] = make_float2(acc[2] * r, acc[3] * r);
        op[2] = make_float2(acc[4] * r, acc[5] * r);
    }
}

// ---------- fused gate kernel: quarter-wave, bf16 rows, pipeline, uniform-beta fast path ----------
__global__ __launch_bounds__(256) void k_fused_gates(const uint32* __restrict__ xtb, const uint32* __restrict__ hNb,
                                                     const float* __restrict__ invx, const float* __restrict__ invh,
                                                     const int* __restrict__ rs, const int* __restrict__ csr_src,
                                                     const float* __restrict__ betas, const float* __restrict__ cold,
                                                     float* __restrict__ hout, float* __restrict__ cout_, int N) {
    int wid = (blockIdx.x * blockDim.x + threadIdx.x) >> 6;
    int lane = threadIdx.x & 63;
    if (wid >= N) return;
    int fi = lane & 15;
    int q  = lane >> 4;
    float bx0 = betas[2], bh0 = betas[3];
    float bx1 = betas[4], bh1 = betas[5];
    float bx2 = betas[6], bh2 = betas[7];
    float bx3 = betas[8], bh3 = betas[9];
    bool uni = (bx0 == bx1) && (bx0 == bx2) && (bx0 == bx3) &&
               (bh0 == bh1) && (bh0 == bh2) && (bh0 == bh3);

    const uint32* xdp = xtb + (size_t)wid * 48 + 3 * fi;
    const uint32* hdp = hNb + (size_t)wid * 48 + 3 * fi;
    float ixd = invx[wid], ihd = invh[wid];
    uint32 xu0 = xdp[0], xu1 = xdp[1], xu2 = xdp[2];
    uint32 hu0 = hdp[0], hu1 = hdp[1], hu2 = hdp[2];
    float xn[6] = {bflo(xu0) * ixd, bfhi(xu0) * ixd, bflo(xu1) * ixd,
                   bfhi(xu1) * ixd, bflo(xu2) * ixd, bfhi(xu2) * ixd};
    float hn[6] = {bflo(hu0) * ihd, bfhi(hu0) * ihd, bflo(hu1) * ihd,
                   bfhi(hu1) * ihd, bflo(hu2) * ihd, bfhi(hu2) * ihd};
    int s0 = rs[wid], s1 = rs[wid + 1];
    size_t rowbase = (size_t)wid * H;

    if (uni) {
        float sxs = fabsf(bx0), shs = fabsf(bh0);
        int nIter = (s1 - s0 + 3) >> 2;
        int idx0 = s0 + q;
        bool vC = idx0 < s1;
        int snC = csr_src[vC ? idx0 : s0];
        const uint32* xrp = xtb + (size_t)snC * 48 + 3 * fi;
        const uint32* hrp = hNb + (size_t)snC * 48 + 3 * fi;
        uint32 xc0 = xrp[0], xc1 = xrp[1], xc2 = xrp[2];
        uint32 hc0 = hrp[0], hc1 = hrp[1], hc2 = hrp[2];
        float isxC = invx[snC], ishC = invh[snC];

        float denX = 0.f, denH = 0.f;
        float aX[6] = {0, 0, 0, 0, 0, 0}, aH[6] = {0, 0, 0, 0, 0, 0};
        for (int it = 0; it < nIter; ++it) {
            int idxN = idx0 + 4 * (it + 1);
            bool vN = idxN < s1;
            int snN = csr_src[vN ? idxN : s0];
            const uint32* xrn = xtb + (size_t)snN * 48 + 3 * fi;
            const uint32* hrn = hNb + (size_t)snN * 48 + 3 * fi;
            uint32 xn0 = xrn[0], xn1 = xrn[1], xn2 = xrn[2];
            uint32 hn0 = hrn[0], hn1 = hrn[1], hn2 = hrn[2];
            float isxN = invx[snN], ishN = invh[snN];
            float xv[6] = {bflo(xc0), bfhi(xc0), bflo(xc1), bfhi(xc1), bflo(xc2), bfhi(xc2)};
            float hv[6] = {bflo(hc0), bfhi(hc0), bflo(hc1), bfhi(hc1), bflo(hc2), bfhi(hc2)};
            float dx = 0.f, dh = 0.f;
#pragma unroll
            for (int j = 0; j < 6; j++) { dx += xv[j] * xn[j]; dh += hv[j] * hn[j]; }
#pragma unroll
            for (int off = 8; off; off >>= 1) {
                dx += __shfl_xor(dx, off, 64);
                dh += __shfl_xor(dh, off, 64);
            }
            float wx = __expf(bx0 * (dx * isxC) - sxs);
            float wh = __expf(bh0 * (dh * ishC) - shs);
            if (!vC) { wx = 0.f; wh = 0.f; }
            denX += wx; denH += wh;
#pragma unroll
            for (int j = 0; j < 6; j++) { aX[j] += wx * xv[j]; aH[j] += wh * hv[j]; }
            xc0 = xn0; xc1 = xn1; xc2 = xn2;
            hc0 = hn0; hc1 = hn1; hc2 = hn2;
            isxC = isxN; ishC = ishN; vC = vN;
        }
        denX += __shfl_xor(denX, 16, 64); denX += __shfl_xor(denX, 32, 64);
        denH += __shfl_xor(denH, 16, 64); denH += __shfl_xor(denH, 32, 64);
#pragma unroll
        for (int j = 0; j < 6; j++) {
            aX[j] += __shfl_xor(aX[j], 16, 64); aX[j] += __shfl_xor(aX[j], 32, 64);
            aH[j] += __shfl_xor(aH[j], 16, 64); aH[j] += __shfl_xor(aH[j], 32, 64);
        }
        if (q == 0) {
            float rX = 1.f / denX, rH = 1.f / denH;
            const float2* cp = (const float2*)(cold + rowbase + 6 * fi);
            float2 cv01 = cp[0], cv23 = cp[1], cv45 = cp[2];
            float cvv[6] = {cv01.x, cv01.y, cv23.x, cv23.y, cv45.x, cv45.y};
            float ho[6], co[6];
#pragma unroll
            for (int j = 0; j < 6; j++) {
                float a   = aX[j] * rX + aH[j] * rH;
                float sig = 1.f / (1.f + __expf(-a));   // f = i = o
                float ct  = tanhf(a);
                float cn  = sig * cvv[j] + sig * ct;
                ho[j] = sig * tanhf(cn);
                co[j] = cn;
            }
            float2* hp = (float2*)(hout + rowbase + 6 * fi);
            float2* cpw = (float2*)(cout_ + rowbase + 6 * fi);
            hp[0] = make_float2(ho[0], ho[1]); hp[1] = make_float2(ho[2], ho[3]); hp[2] = make_float2(ho[4], ho[5]);
            cpw[0] = make_float2(co[0], co[1]); cpw[1] = make_float2(co[2], co[3]); cpw[2] = make_float2(co[4], co[5]);
        }
    } else {
        // general 4-gate path (correctness fallback)
        float sx[4] = {fabsf(bx0), fabsf(bx1), fabsf(bx2), fabsf(bx3)};
        float sh_[4] = {fabsf(bh0), fabsf(bh1), fabsf(bh2), fabsf(bh3)};
        float bxv[4] = {bx0, bx1, bx2, bx3};
        float bhv[4] = {bh0, bh1, bh2, bh3};
        float denX[4] = {0, 0, 0, 0}, denH[4] = {0, 0, 0, 0};
        float aX[4][6], aH[4][6];
#pragma unroll
        for (int g = 0; g < 4; g++)
#pragma unroll
            for (int j = 0; j < 6; j++) { aX[g][j] = 0.f; aH[g][j] = 0.f; }
        for (int s = s0; s < s1; s += 4) {
            int idx = s + q;
            bool valid = idx < s1;
            int sidx = valid ? idx : s0;
            int sn = csr_src[sidx];
            float isx = invx[sn], ish = invh[sn];
            const uint32* xrp = xtb + (size_t)sn * 48 + 3 * fi;
            const uint32* hrp = hNb + (size_t)sn * 48 + 3 * fi;
            uint32 a0 = xrp[0], a1 = xrp[1], a2 = xrp[2];
            uint32 b0 = hrp[0], b1 = hrp[1], b2 = hrp[2];
            float xv[6] = {bflo(a0), bfhi(a0), bflo(a1), bfhi(a1), bflo(a2), bfhi(a2)};
            float hv[6] = {bflo(b0), bfhi(b0), bflo(b1), bfhi(b1), bflo(b2), bfhi(b2)};
            float dx = 0.f, dh = 0.f;
#pragma unroll
            for (int j = 0; j < 6; j++) { dx += xv[j] * xn[j]; dh += hv[j] * hn[j]; }
#pragma unroll
            for (int off = 8; off; off >>= 1) {
                dx += __shfl_xor(dx, off, 64);
                dh += __shfl_xor(dh, off, 64);
            }
            float cx = dx * isx, ch = dh * ish;
#pragma unroll
            for (int g = 0; g < 4; g++) {
                float wx = __expf(bxv[g] * cx - sx[g]);
                float wh = __expf(bhv[g] * ch - sh_[g]);
                if (!valid) { wx = 0.f; wh = 0.f; }
                denX[g] += wx; denH[g] += wh;
#pragma unroll
                for (int j = 0; j < 6; j++) { aX[g][j] += wx * xv[j]; aH[g][j] += wh * hv[j]; }
            }
        }
#pragma unroll
        for (int g = 0; g < 4; g++) {
            denX[g] += __shfl_xor(denX[g], 16, 64); denX[g] += __shfl_xor(denX[g], 32, 64);
            denH[g] += __shfl_xor(denH[g], 16, 64); denH[g] += __shfl_xor(denH[g], 32, 64);
#pragma unroll
            for (int j = 0; j < 6; j++) {
                aX[g][j] += __shfl_xor(aX[g][j], 16, 64); aX[g][j] += __shfl_xor(aX[g][j], 32, 64);
                aH[g][j] += __shfl_xor(aH[g][j], 16, 64); aH[g][j] += __shfl_xor(aH[g][j], 32, 64);
            }
        }
        if (q == 0) {
#pragma unroll
            for (int j = 0; j < 6; j++) {
                int d = 6 * fi + j;
                float a0 = aX[0][j] / denX[0] + aH[0][j] / denH[0];
                float a1 = aX[1][j] / denX[1] + aH[1][j] / denH[1];
                float a2 = aX[2][j] / denX[2] + aH[2][j] / denH[2];
                float a3 = aX[3][j] / denX[3] + aH[3][j] / denH[3];
                float f  = 1.f / (1.f + __expf(-a0));
                float i_ = 1.f / (1.f + __expf(-a1));
                float ct = tanhf(a2);
                float o  = 1.f / (1.f + __expf(-a3));
                float cv = cold[rowbase + d];
                float cn = f * cv + i_ * ct;
                hout[rowbase + d]  = o * tanhf(cn);
                cout_[rowbase + d] = cn;
            }
        }
    }
}

extern "C" void kernel_launch(void* const* d_in, const int* in_sizes, int n_in,
                              void* d_out, int out_size, void* d_ws, size_t ws_size,
                              hipStream_t stream) {
    const float* x        = (const float*)d_in[0];
    const int*   ei       = (const int*)d_in[1];
    const float* h        = (const float*)d_in[2];
    const float* c        = (const float*)d_in[3];
    const float* W_in     = (const float*)d_in[4];
    const float* b_in     = (const float*)d_in[5];
    const float* Wb1      = (const float*)d_in[10];
    const float* bb1      = (const float*)d_in[11];
    const float* Wb2      = (const float*)d_in[12];
    const float* bb2      = (const float*)d_in[13];
    const float* betas    = (const float*)d_in[14];

    int N  = in_sizes[0] / DIN;
    int E  = in_sizes[1] / 2;
    int Et = E + N;
    int NH = N * H;

    char* ws = (char*)d_ws;
    size_t off = 0;
    auto alloc = [&](size_t bytes) -> void* {
        void* p = ws + off;
        off = (off + bytes + 255) & ~(size_t)255;
        return p;
    };
    uint32* xtb  = (uint32*)alloc((size_t)N * 48 * 4);   // xt bf16 rows
    uint32* hNb  = (uint32*)alloc((size_t)N * 48 * 4);   // h_N bf16 rows
    uint32* hb   = (uint32*)alloc((size_t)N * 48 * 4);   // h bf16 rows
    float*  hN0  = (float*)alloc((size_t)NH * 4);        // f32 AGNN(h) output
    int* csr_src = (int*)alloc((size_t)Et * 4);
    int* deg     = (int*)alloc((size_t)N * 4);
    int* rs      = (int*)alloc((size_t)(N + 1) * 4);
    int* cur     = (int*)alloc((size_t)N * 4);
    int* bsum    = (int*)alloc(64 * 4);
    float* inv_h  = (float*)alloc((size_t)N * 4);
    float* inv_xt = (float*)alloc((size_t)N * 4);
    float* inv_hN = (float*)alloc((size_t)N * 4);

    int nb = (N + 1023) / 1024;
    int gblk = (N + 63) / 64;

    hipMemsetAsync(deg, 0, (size_t)N * 4, stream);
    k_hist<<<(Et + 255) / 256, 256, 0, stream>>>(ei, E, N, deg);
    k_scanA<<<nb, 256, 0, stream>>>(deg, rs, bsum, N);
    k_scanB<<<1, 64, 0, stream>>>(bsum, nb);
    k_scanC<<<(N + 255) / 256, 256, 0, stream>>>(rs, cur, bsum, N, Et);
    k_scatter<<<(Et + 255) / 256, 256, 0, stream>>>(ei, E, N, cur, csr_src);

    k_gemm_in_mfma<<<gblk, 256, 0, stream>>>(x, W_in, b_in, xtb, N);
    k_cvt_h<<<(N + 3) / 4, 256, 0, stream>>>(h, hb, inv_h, N);
    k_fused_h<<<(N + 3) / 4, 256, 0, stream>>>(hb, inv_h, rs, csr_src, betas, hN0, N);

    k_gemm_gate_mfma<<<gblk, 256, 0, stream>>>(hb, hN0, h, Wb1, Wb2, bb1, bb2, hNb, N);

    k_invnorm_b<<<(N + 3) / 4, 256, 0, stream>>>(xtb, inv_xt, N);
    k_invnorm_b<<<(N + 3) / 4, 256, 0, stream>>>(hNb, inv_hN, N);

    float* hout = (float*)d_out;
    float* cout_ = (float*)d_out + NH;
    k_fused_gates<<<(N + 3) / 4, 256, 0, stream>>>(xtb, hNb, inv_xt, inv_hN, rs, csr_src, betas, c, hout, cout_, N);
}

// Round 10
// 302.122 us; speedup vs baseline: 3.0482x; 1.0805x over previous
//
#include <hip/hip_runtime.h>
#include <hip/hip_bf16.h>

#define H 96
#define DIN 256

typedef unsigned int uint32;
typedef __attribute__((ext_vector_type(8))) short bf16x8;
typedef __attribute__((ext_vector_type(4))) float f32x4;

__device__ __forceinline__ float bflo(uint32 u) { return __uint_as_float(u << 16); }
__device__ __forceinline__ float bfhi(uint32 u) { return __uint_as_float(u & 0xffff0000u); }
__device__ __forceinline__ uint32 packbf(float a, float b) {
    __hip_bfloat16 x = __float2bfloat16(a), y = __float2bfloat16(b);
    unsigned short lo = *reinterpret_cast<unsigned short*>(&x);
    unsigned short hi = *reinterpret_cast<unsigned short*>(&y);
    return (uint32)lo | ((uint32)hi << 16);
}
__device__ __forceinline__ float bfround(float a) {
    return __bfloat162float(__float2bfloat16(a));
}

// ---------- CSR build ----------
__global__ void k_hist(const int* __restrict__ ei, int E, int N, int* __restrict__ deg) {
    int e = blockIdx.x * blockDim.x + threadIdx.x;
    int Et = E + N;
    if (e >= Et) return;
    int dst = (e < E) ? ei[E + e] : (e - E);
    atomicAdd(&deg[dst], 1);
}

__global__ __launch_bounds__(256) void k_scanA(const int* __restrict__ deg, int* __restrict__ rs,
                                               int* __restrict__ bsum, int n) {
    __shared__ int sh[256];
    int t = threadIdx.x;
    int base = blockIdx.x * 1024 + t * 4;
    int v[4];
    int s = 0;
#pragma unroll
    for (int j = 0; j < 4; j++) { v[j] = (base + j < n) ? deg[base + j] : 0; s += v[j]; }
    sh[t] = s;
    __syncthreads();
    for (int off = 1; off < 256; off <<= 1) {
        int tmp = (t >= off) ? sh[t - off] : 0;
        __syncthreads();
        sh[t] += tmp;
        __syncthreads();
    }
    int excl = sh[t] - s;
#pragma unroll
    for (int j = 0; j < 4; j++) {
        if (base + j < n) rs[base + j] = excl;
        excl += v[j];
    }
    if (t == 255) bsum[blockIdx.x] = sh[255];
}

__global__ void k_scanB(int* __restrict__ bsum, int nb) {
    int l = threadIdx.x;
    int orig = (l < nb) ? bsum[l] : 0;
    int v = orig;
#pragma unroll
    for (int off = 1; off < 64; off <<= 1) {
        int u = __shfl_up(v, off, 64);
        if (l >= off) v += u;
    }
    if (l < nb) bsum[l] = v - orig;
}

__global__ void k_scanC(int* __restrict__ rs, int* __restrict__ cur, const int* __restrict__ bsum,
                        int n, int total) {
    int i = blockIdx.x * blockDim.x + threadIdx.x;
    if (i < n) {
        int r = rs[i] + bsum[i >> 10];
        rs[i] = r;
        cur[i] = r;
    }
    if (i == 0) rs[n] = total;
}

__global__ void k_scatter(const int* __restrict__ ei, int E, int N,
                          int* __restrict__ cur, int* __restrict__ csr_src) {
    int e = blockIdx.x * blockDim.x + threadIdx.x;
    int Et = E + N;
    if (e >= Et) return;
    int src, dst;
    if (e < E) { src = ei[e]; dst = ei[E + e]; }
    else       { src = e - E; dst = e - E; }
    int pos = atomicAdd(&cur[dst], 1);
    csr_src[pos] = src;
}

// ---------- MFMA GEMM: xt half of ftb + inv2.x ----------
// block: 64 rows x 96 cols, 4 waves. K chunked by 128. Epilogue fuses norm.
__global__ __launch_bounds__(256) void k_gemm_in_mfma(const float* __restrict__ x, const float* __restrict__ W,
                                                      const float* __restrict__ b, uint32* __restrict__ ftb,
                                                      float* __restrict__ inv2, int N) {
    __shared__ uint32 As[64 * 68];
    __shared__ uint32 Ws[96 * 68];
    int tid = threadIdx.x;
    int lane = tid & 63;
    int w = tid >> 6;
    int row0 = blockIdx.x * 64;
    int n = lane & 15, g = lane >> 4;

    f32x4 acc[6];
#pragma unroll
    for (int t = 0; t < 6; t++) acc[t] = (f32x4){0.f, 0.f, 0.f, 0.f};

    for (int kc = 0; kc < DIN; kc += 128) {
        for (int i = tid; i < 64 * 32; i += 256) {
            int r = i >> 5, seg = i & 31;
            int grow = row0 + r;
            float4 v = (grow < N) ? *(const float4*)(x + (size_t)grow * DIN + kc + seg * 4)
                                  : make_float4(0.f, 0.f, 0.f, 0.f);
            As[r * 68 + seg * 2]     = packbf(v.x, v.y);
            As[r * 68 + seg * 2 + 1] = packbf(v.z, v.w);
        }
        for (int i = tid; i < 96 * 32; i += 256) {
            int r = i >> 5, seg = i & 31;
            float4 v = *(const float4*)(W + (size_t)r * DIN + kc + seg * 4);
            Ws[r * 68 + seg * 2]     = packbf(v.x, v.y);
            Ws[r * 68 + seg * 2 + 1] = packbf(v.z, v.w);
        }
        __syncthreads();
#pragma unroll
        for (int s = 0; s < 4; s++) {
            int kb = s * 16 + g * 4;
            bf16x8 a = *(const bf16x8*)&As[(16 * w + n) * 68 + kb];
#pragma unroll
            for (int t = 0; t < 6; t++) {
                bf16x8 bb = *(const bf16x8*)&Ws[(16 * t + n) * 68 + kb];
                acc[t] = __builtin_amdgcn_mfma_f32_16x16x32_bf16(a, bb, acc[t], 0, 0, 0);
            }
        }
        __syncthreads();
    }
    // epilogue: bias, rounded pack to ftb xt-half, fused norm
    float ss[4] = {0.f, 0.f, 0.f, 0.f};
#pragma unroll
    for (int t = 0; t < 6; t++) {
        int col = 16 * t + n;
        float bv = b[col];
#pragma unroll
        for (int r = 0; r < 4; r++) {
            int grow = row0 + 16 * w + g * 4 + r;
            float v = acc[t][r] + bv;
            float vb = bfround(v);
            ss[r] += vb * vb;
            float p = __shfl_xor(v, 1, 64);
            if ((n & 1) == 0 && grow < N)
                ftb[(size_t)grow * 96 + 8 * t + (n >> 1)] = packbf(v, p);
        }
    }
#pragma unroll
    for (int r = 0; r < 4; r++) {
#pragma unroll
        for (int off = 1; off < 16; off <<= 1) ss[r] += __shfl_xor(ss[r], off, 64);
        int grow = row0 + 16 * w + g * 4 + r;
        if (n == 0 && grow < N) inv2[2 * grow] = 1.f / fmaxf(sqrtf(ss[r]), 1e-12f);
    }
}

// ---------- MFMA GEMM: h_N = h + tanh([h|A]@[Wb1|Wb2]^T + b) -> hN half of ftb + inv2.y ----------
__global__ __launch_bounds__(256) void k_gemm_gate_mfma(const uint32* __restrict__ hb, const uint32* __restrict__ hN0b,
                                                        const float* __restrict__ h,
                                                        const float* __restrict__ W1, const float* __restrict__ W2,
                                                        const float* __restrict__ b1, const float* __restrict__ b2,
                                                        uint32* __restrict__ ftb, float* __restrict__ inv2, int N) {
    __shared__ uint32 As[64 * 52];
    __shared__ uint32 Ws[96 * 52];
    int tid = threadIdx.x;
    int lane = tid & 63;
    int w = tid >> 6;
    int row0 = blockIdx.x * 64;
    int n = lane & 15, g = lane >> 4;

    f32x4 acc[6];
#pragma unroll
    for (int t = 0; t < 6; t++) acc[t] = (f32x4){0.f, 0.f, 0.f, 0.f};

    for (int chunk = 0; chunk < 2; chunk++) {
        // stage A tile from bf16 table (hb or hN0b), both 48 u32/row
        {
            const uint32* src = chunk ? hN0b : hb;
            int r = tid >> 2, j = tid & 3;
            int grow = row0 + r;
            if (grow < N) {
#pragma unroll
                for (int m = 0; m < 3; m++) {
                    uint4 u = *(const uint4*)(src + (size_t)grow * 48 + j * 12 + m * 4);
                    *(uint4*)&As[r * 52 + j * 12 + m * 4] = u;
                }
            } else {
#pragma unroll
                for (int m = 0; m < 12; m++) As[r * 52 + j * 12 + m] = 0u;
            }
        }
        {
            const float* Wsrc = chunk ? W2 : W1;
            for (int i = tid; i < 96 * 24; i += 256) {
                int r = i / 24, seg = i % 24;
                float4 v = *(const float4*)(Wsrc + (size_t)r * H + seg * 4);
                Ws[r * 52 + seg * 2]     = packbf(v.x, v.y);
                Ws[r * 52 + seg * 2 + 1] = packbf(v.z, v.w);
            }
        }
        __syncthreads();
#pragma unroll
        for (int s = 0; s < 3; s++) {
            int kb = s * 16 + g * 4;
            bf16x8 a = *(const bf16x8*)&As[(16 * w + n) * 52 + kb];
#pragma unroll
            for (int t = 0; t < 6; t++) {
                bf16x8 bb = *(const bf16x8*)&Ws[(16 * t + n) * 52 + kb];
                acc[t] = __builtin_amdgcn_mfma_f32_16x16x32_bf16(a, bb, acc[t], 0, 0, 0);
            }
        }
        __syncthreads();
    }
    // epilogue: tanh + h add, pack to ftb hN-half, fused norm
    float ss[4] = {0.f, 0.f, 0.f, 0.f};
#pragma unroll
    for (int t = 0; t < 6; t++) {
        int col = 16 * t + n;
        float bsum = b1[col] + b2[col];
#pragma unroll
        for (int r = 0; r < 4; r++) {
            int grow = row0 + 16 * w + g * 4 + r;
            float hval = (grow < N) ? h[(size_t)grow * H + col] : 0.f;
            float v = hval + tanhf(acc[t][r] + bsum);
            float vb = bfround(v);
            ss[r] += vb * vb;
            float p = __shfl_xor(v, 1, 64);
            if ((n & 1) == 0 && grow < N)
                ftb[(size_t)grow * 96 + 48 + 8 * t + (n >> 1)] = packbf(v, p);
        }
    }
#pragma unroll
    for (int r = 0; r < 4; r++) {
#pragma unroll
        for (int off = 1; off < 16; off <<= 1) ss[r] += __shfl_xor(ss[r], off, 64);
        int grow = row0 + 16 * w + g * 4 + r;
        if (n == 0 && grow < N) inv2[2 * grow + 1] = 1.f / fmaxf(sqrtf(ss[r]), 1e-12f);
    }
}

// ---------- h (f32) -> bf16 table + inverse norm ----------
__global__ __launch_bounds__(256) void k_cvt_h(const float* __restrict__ h, uint32* __restrict__ hb,
                                               float* __restrict__ inv, int N) {
    int wid = (blockIdx.x * blockDim.x + threadIdx.x) >> 6;
    int lane = threadIdx.x & 63;
    if (wid >= N) return;
    const float2* row = (const float2*)(h + (size_t)wid * H);
    float ss = 0.f;
    if (lane < 48) {
        float2 v = row[lane];
        uint32 p = packbf(v.x, v.y);
        hb[(size_t)wid * 48 + lane] = p;
        float a = bflo(p), b = bfhi(p);
        ss = a * a + b * b;
    }
#pragma unroll
    for (int off = 32; off; off >>= 1) ss += __shfl_xor(ss, off, 64);
    if (lane == 0) inv[wid] = 1.f / fmaxf(sqrtf(ss), 1e-12f);
}

// ---------- fused AGNN on h: 8 lanes/edge x 8 edges/iter, bf16 in/out ----------
__global__ __launch_bounds__(256) void k_fused_h(const uint32* __restrict__ hb, const float* __restrict__ invn,
                                                 const int* __restrict__ rs, const int* __restrict__ csr_src,
                                                 const float* __restrict__ betas, uint32* __restrict__ outb, int N) {
    int wid = (blockIdx.x * blockDim.x + threadIdx.x) >> 6;
    int lane = threadIdx.x & 63;
    if (wid >= N) return;
    int d8 = lane & 7;   // dim block: dims [12*d8, 12*d8+12)
    int e8 = lane >> 3;  // edge slot in [0,8)
    float beta = betas[1];
    float shift = fabsf(beta);
    const uint32* dbase = hb + (size_t)wid * 48 + 6 * d8;
    float invd = invn[wid];
    uint2 dw0 = *(const uint2*)dbase, dw1 = *(const uint2*)(dbase + 2), dw2 = *(const uint2*)(dbase + 4);
    float dn[12] = {bflo(dw0.x) * invd, bfhi(dw0.x) * invd, bflo(dw0.y) * invd, bfhi(dw0.y) * invd,
                    bflo(dw1.x) * invd, bfhi(dw1.x) * invd, bflo(dw1.y) * invd, bfhi(dw1.y) * invd,
                    bflo(dw2.x) * invd, bfhi(dw2.x) * invd, bflo(dw2.y) * invd, bfhi(dw2.y) * invd};
    int s0 = rs[wid], s1 = rs[wid + 1];
    int nIter = (s1 - s0 + 7) >> 3;
    int idx0 = s0 + e8;
    bool vC = idx0 < s1;
    int snC = csr_src[vC ? idx0 : s0];
    const uint32* rb = hb + (size_t)snC * 48 + 6 * d8;
    uint2 c0 = *(const uint2*)rb, c1 = *(const uint2*)(rb + 2), c2 = *(const uint2*)(rb + 4);
    float invC = invn[snC];

    float den = 0.f;
    float acc[12] = {0, 0, 0, 0, 0, 0, 0, 0, 0, 0, 0, 0};
    for (int it = 0; it < nIter; ++it) {
        int idxN = idx0 + 8 * (it + 1);
        bool vN = idxN < s1;
        int snN = csr_src[vN ? idxN : s0];
        const uint32* rbn = hb + (size_t)snN * 48 + 6 * d8;
        uint2 n0 = *(const uint2*)rbn, n1 = *(const uint2*)(rbn + 2), n2 = *(const uint2*)(rbn + 4);
        float invN = invn[snN];
        float v[12] = {bflo(c0.x), bfhi(c0.x), bflo(c0.y), bfhi(c0.y),
                       bflo(c1.x), bfhi(c1.x), bflo(c1.y), bfhi(c1.y),
                       bflo(c2.x), bfhi(c2.x), bflo(c2.y), bfhi(c2.y)};
        float d = 0.f;
#pragma unroll
        for (int j = 0; j < 12; j++) d += v[j] * dn[j];
        d += __shfl_xor(d, 1, 64);
        d += __shfl_xor(d, 2, 64);
        d += __shfl_xor(d, 4, 64);
        float w = __expf(beta * (d * invC) - shift);
        if (!vC) w = 0.f;
        den += w;
#pragma unroll
        for (int j = 0; j < 12; j++) acc[j] += w * v[j];
        c0 = n0; c1 = n1; c2 = n2; invC = invN; vC = vN;
    }
    den += __shfl_xor(den, 8, 64);
    den += __shfl_xor(den, 16, 64);
    den += __shfl_xor(den, 32, 64);
#pragma unroll
    for (int j = 0; j < 12; j++) {
        acc[j] += __shfl_xor(acc[j], 8, 64);
        acc[j] += __shfl_xor(acc[j], 16, 64);
        acc[j] += __shfl_xor(acc[j], 32, 64);
    }
    if (e8 == 0) {
        float r = 1.f / den;
        uint32* op = outb + (size_t)wid * 48 + 6 * d8;
        uint2 o0, o1, o2;
        o0.x = packbf(acc[0] * r, acc[1] * r);  o0.y = packbf(acc[2] * r, acc[3] * r);
        o1.x = packbf(acc[4] * r, acc[5] * r);  o1.y = packbf(acc[6] * r, acc[7] * r);
        o2.x = packbf(acc[8] * r, acc[9] * r);  o2.y = packbf(acc[10] * r, acc[11] * r);
        *(uint2*)op = o0; *(uint2*)(op + 2) = o1; *(uint2*)(op + 4) = o2;
    }
}

// ---------- fused gate kernel: merged table, role-split lanes, uniform-beta fast path ----------
__global__ __launch_bounds__(256) void k_fused_gates(const uint32* __restrict__ ftb, const float* __restrict__ inv2,
                                                     const int* __restrict__ rs, const int* __restrict__ csr_src,
                                                     const float* __restrict__ betas, const float* __restrict__ cold,
                                                     float* __restrict__ hout, float* __restrict__ cout_, int N) {
    int wid = (blockIdx.x * blockDim.x + threadIdx.x) >> 6;
    int lane = threadIdx.x & 63;
    if (wid >= N) return;
    float bx0 = betas[2], bh0 = betas[3];
    float bx1 = betas[4], bh1 = betas[5];
    float bx2 = betas[6], bh2 = betas[7];
    float bx3 = betas[8], bh3 = betas[9];
    bool uni = (bx0 == bx1) && (bx0 == bx2) && (bx0 == bx3) &&
               (bh0 == bh1) && (bh0 == bh2) && (bh0 == bh3);
    int s0 = rs[wid], s1 = rs[wid + 1];
    size_t rowbase = (size_t)wid * H;

    if (uni) {
        int l16 = lane & 15, q = lane >> 4;
        int sub = l16 >> 3;      // 0 = xt, 1 = hN
        int d8  = l16 & 7;       // dims [12*d8, 12*d8+12) of its feature
        float bsel = sub ? bh0 : bx0;
        float ssel = fabsf(bsel);
        const uint32* dbase = ftb + (size_t)wid * 96 + sub * 48 + 6 * d8;
        float invd = inv2[2 * wid + sub];
        uint2 dw0 = *(const uint2*)dbase, dw1 = *(const uint2*)(dbase + 2), dw2 = *(const uint2*)(dbase + 4);
        float dn[12] = {bflo(dw0.x) * invd, bfhi(dw0.x) * invd, bflo(dw0.y) * invd, bfhi(dw0.y) * invd,
                        bflo(dw1.x) * invd, bfhi(dw1.x) * invd, bflo(dw1.y) * invd, bfhi(dw1.y) * invd,
                        bflo(dw2.x) * invd, bfhi(dw2.x) * invd, bflo(dw2.y) * invd, bfhi(dw2.y) * invd};
        int nIter = (s1 - s0 + 3) >> 2;
        int idx0 = s0 + q;
        bool vC = idx0 < s1;
        int snC = csr_src[vC ? idx0 : s0];
        const uint32* rb = ftb + (size_t)snC * 96 + sub * 48 + 6 * d8;
        uint2 c0 = *(const uint2*)rb, c1 = *(const uint2*)(rb + 2), c2 = *(const uint2*)(rb + 4);
        float isC = inv2[2 * snC + sub];

        float den = 0.f;
        float acc[12] = {0, 0, 0, 0, 0, 0, 0, 0, 0, 0, 0, 0};
        for (int it = 0; it < nIter; ++it) {
            int idxN = idx0 + 4 * (it + 1);
            bool vN = idxN < s1;
            int snN = csr_src[vN ? idxN : s0];
            const uint32* rbn = ftb + (size_t)snN * 96 + sub * 48 + 6 * d8;
            uint2 n0 = *(const uint2*)rbn, n1 = *(const uint2*)(rbn + 2), n2 = *(const uint2*)(rbn + 4);
            float isN = inv2[2 * snN + sub];
            float v[12] = {bflo(c0.x), bfhi(c0.x), bflo(c0.y), bfhi(c0.y),
                           bflo(c1.x), bfhi(c1.x), bflo(c1.y), bfhi(c1.y),
                           bflo(c2.x), bfhi(c2.x), bflo(c2.y), bfhi(c2.y)};
            float d = 0.f;
#pragma unroll
            for (int j = 0; j < 12; j++) d += v[j] * dn[j];
            d += __shfl_xor(d, 1, 64);
            d += __shfl_xor(d, 2, 64);
            d += __shfl_xor(d, 4, 64);
            float w = __expf(bsel * (d * isC) - ssel);
            if (!vC) w = 0.f;
            den += w;
#pragma unroll
            for (int j = 0; j < 12; j++) acc[j] += w * v[j];
            c0 = n0; c1 = n1; c2 = n2; isC = isN; vC = vN;
        }
        // cross-quarter reduce (same role lanes)
        den += __shfl_xor(den, 16, 64);
        den += __shfl_xor(den, 32, 64);
#pragma unroll
        for (int j = 0; j < 12; j++) {
            acc[j] += __shfl_xor(acc[j], 16, 64);
            acc[j] += __shfl_xor(acc[j], 32, 64);
        }
        // exchange xt<->hN halves
        float oden = __shfl_xor(den, 8, 64);
        float oacc[12];
#pragma unroll
        for (int j = 0; j < 12; j++) oacc[j] = __shfl_xor(acc[j], 8, 64);
        if (q == 0 && sub == 0) {
            float rX = 1.f / den, rH = 1.f / oden;
            size_t ob = rowbase + 12 * d8;
            float4 cv0 = *(const float4*)(cold + ob);
            float4 cv1 = *(const float4*)(cold + ob + 4);
            float4 cv2 = *(const float4*)(cold + ob + 8);
            float cvv[12] = {cv0.x, cv0.y, cv0.z, cv0.w, cv1.x, cv1.y, cv1.z, cv1.w,
                             cv2.x, cv2.y, cv2.z, cv2.w};
            float ho[12], co[12];
#pragma unroll
            for (int j = 0; j < 12; j++) {
                float a   = acc[j] * rX + oacc[j] * rH;
                float sig = 1.f / (1.f + __expf(-a));   // f = i = o
                float ct  = tanhf(a);
                float cn  = sig * cvv[j] + sig * ct;
                ho[j] = sig * tanhf(cn);
                co[j] = cn;
            }
            *(float4*)(hout + ob)     = make_float4(ho[0], ho[1], ho[2], ho[3]);
            *(float4*)(hout + ob + 4) = make_float4(ho[4], ho[5], ho[6], ho[7]);
            *(float4*)(hout + ob + 8) = make_float4(ho[8], ho[9], ho[10], ho[11]);
            *(float4*)(cout_ + ob)     = make_float4(co[0], co[1], co[2], co[3]);
            *(float4*)(cout_ + ob + 4) = make_float4(co[4], co[5], co[6], co[7]);
            *(float4*)(cout_ + ob + 8) = make_float4(co[8], co[9], co[10], co[11]);
        }
    } else {
        // general 4-gate path (correctness fallback; betas arbitrary)
        int fi = lane & 15;
        int q  = lane >> 4;
        float ixd = inv2[2 * wid], ihd = inv2[2 * wid + 1];
        const uint32* xdp = ftb + (size_t)wid * 96 + 3 * fi;
        const uint32* hdp = ftb + (size_t)wid * 96 + 48 + 3 * fi;
        uint32 xu0 = xdp[0], xu1 = xdp[1], xu2 = xdp[2];
        uint32 hu0 = hdp[0], hu1 = hdp[1], hu2 = hdp[2];
        float xn[6] = {bflo(xu0) * ixd, bfhi(xu0) * ixd, bflo(xu1) * ixd,
                       bfhi(xu1) * ixd, bflo(xu2) * ixd, bfhi(xu2) * ixd};
        float hn[6] = {bflo(hu0) * ihd, bfhi(hu0) * ihd, bflo(hu1) * ihd,
                       bfhi(hu1) * ihd, bflo(hu2) * ihd, bfhi(hu2) * ihd};
        float sx[4] = {fabsf(bx0), fabsf(bx1), fabsf(bx2), fabsf(bx3)};
        float sh_[4] = {fabsf(bh0), fabsf(bh1), fabsf(bh2), fabsf(bh3)};
        float bxv[4] = {bx0, bx1, bx2, bx3};
        float bhv[4] = {bh0, bh1, bh2, bh3};
        float denX[4] = {0, 0, 0, 0}, denH[4] = {0, 0, 0, 0};
        float aX[4][6], aH[4][6];
#pragma unroll
        for (int g = 0; g < 4; g++)
#pragma unroll
            for (int j = 0; j < 6; j++) { aX[g][j] = 0.f; aH[g][j] = 0.f; }
        for (int s = s0; s < s1; s += 4) {
            int idx = s + q;
            bool valid = idx < s1;
            int sidx = valid ? idx : s0;
            int sn = csr_src[sidx];
            float isx = inv2[2 * sn], ish = inv2[2 * sn + 1];
            const uint32* xrp = ftb + (size_t)sn * 96 + 3 * fi;
            const uint32* hrp = ftb + (size_t)sn * 96 + 48 + 3 * fi;
            uint32 a0 = xrp[0], a1 = xrp[1], a2 = xrp[2];
            uint32 b0 = hrp[0], b1 = hrp[1], b2 = hrp[2];
            float xv[6] = {bflo(a0), bfhi(a0), bflo(a1), bfhi(a1), bflo(a2), bfhi(a2)};
            float hv[6] = {bflo(b0), bfhi(b0), bflo(b1), bfhi(b1), bflo(b2), bfhi(b2)};
            float dx = 0.f, dh = 0.f;
#pragma unroll
            for (int j = 0; j < 6; j++) { dx += xv[j] * xn[j]; dh += hv[j] * hn[j]; }
#pragma unroll
            for (int off = 8; off; off >>= 1) {
                dx += __shfl_xor(dx, off, 64);
                dh += __shfl_xor(dh, off, 64);
            }
            float cx = dx * isx, ch = dh * ish;
#pragma unroll
            for (int g = 0; g < 4; g++) {
                float wx = __expf(bxv[g] * cx - sx[g]);
                float wh = __expf(bhv[g] * ch - sh_[g]);
                if (!valid) { wx = 0.f; wh = 0.f; }
                denX[g] += wx; denH[g] += wh;
#pragma unroll
                for (int j = 0; j < 6; j++) { aX[g][j] += wx * xv[j]; aH[g][j] += wh * hv[j]; }
            }
        }
#pragma unroll
        for (int g = 0; g < 4; g++) {
            denX[g] += __shfl_xor(denX[g], 16, 64); denX[g] += __shfl_xor(denX[g], 32, 64);
            denH[g] += __shfl_xor(denH[g], 16, 64); denH[g] += __shfl_xor(denH[g], 32, 64);
#pragma unroll
            for (int j = 0; j < 6; j++) {
                aX[g][j] += __shfl_xor(aX[g][j], 16, 64); aX[g][j] += __shfl_xor(aX[g][j], 32, 64);
                aH[g][j] += __shfl_xor(aH[g][j], 16, 64); aH[g][j] += __shfl_xor(aH[g][j], 32, 64);
            }
        }
        if (q == 0) {
#pragma unroll
            for (int j = 0; j < 6; j++) {
                int d = 6 * fi + j;
                float a0 = aX[0][j] / denX[0] + aH[0][j] / denH[0];
                float a1 = aX[1][j] / denX[1] + aH[1][j] / denH[1];
                float a2 = aX[2][j] / denX[2] + aH[2][j] / denH[2];
                float a3 = aX[3][j] / denX[3] + aH[3][j] / denH[3];
                float f  = 1.f / (1.f + __expf(-a0));
                float i_ = 1.f / (1.f + __expf(-a1));
                float ct = tanhf(a2);
                float o  = 1.f / (1.f + __expf(-a3));
                float cv = cold[rowbase + d];
                float cn = f * cv + i_ * ct;
                hout[rowbase + d]  = o * tanhf(cn);
                cout_[rowbase + d] = cn;
            }
        }
    }
}

extern "C" void kernel_launch(void* const* d_in, const int* in_sizes, int n_in,
                              void* d_out, int out_size, void* d_ws, size_t ws_size,
                              hipStream_t stream) {
    const float* x        = (const float*)d_in[0];
    const int*   ei       = (const int*)d_in[1];
    const float* h        = (const float*)d_in[2];
    const float* c        = (const float*)d_in[3];
    const float* W_in     = (const float*)d_in[4];
    const float* b_in     = (const float*)d_in[5];
    const float* Wb1      = (const float*)d_in[10];
    const float* bb1      = (const float*)d_in[11];
    const float* Wb2      = (const float*)d_in[12];
    const float* bb2      = (const float*)d_in[13];
    const float* betas    = (const float*)d_in[14];

    int N  = in_sizes[0] / DIN;
    int E  = in_sizes[1] / 2;
    int Et = E + N;
    int NH = N * H;

    char* ws = (char*)d_ws;
    size_t off = 0;
    auto alloc = [&](size_t bytes) -> void* {
        void* p = ws + off;
        off = (off + bytes + 255) & ~(size_t)255;
        return p;
    };
    uint32* ftb  = (uint32*)alloc((size_t)N * 96 * 4);   // merged bf16 rows: [xt(48 u32) | hN(48 u32)]
    uint32* hb   = (uint32*)alloc((size_t)N * 48 * 4);   // h bf16 rows
    uint32* hN0b = (uint32*)alloc((size_t)N * 48 * 4);   // AGNN(h) bf16 rows
    float* inv2  = (float*)alloc((size_t)N * 2 * 4);     // (inv_xt, inv_hN) pairs
    int* csr_src = (int*)alloc((size_t)Et * 4);
    int* deg     = (int*)alloc((size_t)N * 4);
    int* rs      = (int*)alloc((size_t)(N + 1) * 4);
    int* cur     = (int*)alloc((size_t)N * 4);
    int* bsum    = (int*)alloc(64 * 4);
    float* inv_h = (float*)alloc((size_t)N * 4);

    int nb = (N + 1023) / 1024;
    int gblk = (N + 63) / 64;

    hipMemsetAsync(deg, 0, (size_t)N * 4, stream);
    k_hist<<<(Et + 255) / 256, 256, 0, stream>>>(ei, E, N, deg);
    k_scanA<<<nb, 256, 0, stream>>>(deg, rs, bsum, N);
    k_scanB<<<1, 64, 0, stream>>>(bsum, nb);
    k_scanC<<<(N + 255) / 256, 256, 0, stream>>>(rs, cur, bsum, N, Et);
    k_scatter<<<(Et + 255) / 256, 256, 0, stream>>>(ei, E, N, cur, csr_src);

    k_gemm_in_mfma<<<gblk, 256, 0, stream>>>(x, W_in, b_in, ftb, inv2, N);
    k_cvt_h<<<(N + 3) / 4, 256, 0, stream>>>(h, hb, inv_h, N);
    k_fused_h<<<(N + 3) / 4, 256, 0, stream>>>(hb, inv_h, rs, csr_src, betas, hN0b, N);

    k_gemm_gate_mfma<<<gblk, 256, 0, stream>>>(hb, hN0b, h, Wb1, Wb2, bb1, bb2, ftb, inv2, N);

    float* hout = (float*)d_out;
    float* cout_ = (float*)d_out + NH;
    k_fused_gates<<<(N + 3) / 4, 256, 0, stream>>>(ftb, inv2, rs, csr_src, betas, c, hout, cout_, N);
}